// Round 1
// baseline (1196.300 us; speedup 1.0000x reference)
//
#include <hip/hip_runtime.h>
#include <cstdint>
#include <cstddef>

// ---------------- problem constants ----------------
#define T_SEQ 2048
#define C_DIM 1024
#define H_HEADS 16
#define D_HEAD 64
#define FF_DIM 4096
#define V_VOCAB 32000
#define L_LAYERS 2
#define QC 512            // query chunk for scores buffer

typedef unsigned short u16;
typedef short bf16x8 __attribute__((ext_vector_type(8)));
typedef float f32x4 __attribute__((ext_vector_type(4)));

__device__ inline u16 f2bf(float f) {
  unsigned u = __float_as_uint(f);
  u += 0x7fffu + ((u >> 16) & 1u);   // RNE
  return (u16)(u >> 16);
}
__device__ inline float bf2f(u16 h) { return __uint_as_float(((unsigned)h) << 16); }

// ---------------- device arena (all scratch; avoids ws_size assumptions) ----
#define OFF_WTEBF   0ULL                    // 32000*1024 bf16
#define OFF_ATTNBF  65536000ULL             // 2*2048*1024 bf16
#define OFF_FCBF    73924608ULL             // 2*4096*1024 bf16
#define OFF_PRJBF   90701824ULL             // 2*1024*4096 bf16
#define OFF_X       107479040ULL            // 2048*1024 f32 (residual stream)
#define OFF_HBF     115867648ULL            // 2048*1024 bf16 (LN out)
#define OFF_QKBF    120061952ULL            // 2048*2048 bf16 (q|k)
#define OFF_VT      128450560ULL            // 16*64*2048 bf16 (V^T per head)
#define OFF_Y       132644864ULL            // 2048*1024 f32 (attn out pre-proj)
#define OFF_SC      141033472ULL            // 16*QC*2048 f32 (scores chunk)
#define OFF_PBF     208142336ULL            // 16*2048*2048 bf16 (softmax P)
#define OFF_FBF     342360064ULL            // 2048*4096 bf16 (gelu(fc) out)
#define ARENA_BYTES 359137280ULL

__device__ __align__(1024) unsigned char g_arena[ARENA_BYTES];

// ---------------- tiny kernels ----------------
__global__ void cvt_bf16_k(const float4* __restrict__ in, ushort4* __restrict__ out, int n4) {
  int i = blockIdx.x * 256 + threadIdx.x;
  if (i < n4) {
    float4 v = in[i];
    out[i] = make_ushort4(f2bf(v.x), f2bf(v.y), f2bf(v.z), f2bf(v.w));
  }
}

__global__ void embed_k(const int* __restrict__ idx, const float4* __restrict__ wte,
                        float4* __restrict__ x) {
  int t = blockIdx.x;
  int r = idx[t];
  x[(size_t)t * 256 + threadIdx.x] = wte[(size_t)r * 256 + threadIdx.x];
}

// per-(token, head) LayerNorm over 64 channels, scalar w/b per head; bf16 out
__global__ void symln_k(const float* __restrict__ x, const float* __restrict__ w,
                        const float* __restrict__ b, u16* __restrict__ out) {
  int t = blockIdx.x;
  int wv = threadIdx.x >> 6, lane = threadIdx.x & 63;
  #pragma unroll
  for (int hh = 0; hh < 4; hh++) {
    int h = wv * 4 + hh;
    float v = x[(size_t)t * C_DIM + h * 64 + lane];
    float s = v, s2 = v * v;
    #pragma unroll
    for (int m = 32; m; m >>= 1) { s += __shfl_xor(s, m); s2 += __shfl_xor(s2, m); }
    float mu = s * (1.f / 64.f);
    float var = s2 * (1.f / 64.f) - mu * mu;
    float n = (v - mu) * rsqrtf(var + 1e-5f) * w[h] + b[h];
    out[(size_t)t * C_DIM + h * 64 + lane] = f2bf(n);
  }
}

// v[t,h,e] = sum_d h_in[t,h,d]*v_tmp[h,e,d]  -> stored transposed vt[h][e][t] (bf16)
__global__ void vcompute_k(const u16* __restrict__ hbf, const float* __restrict__ vtmp,
                           u16* __restrict__ vt) {
  int h = blockIdx.y, t0 = blockIdx.x * 4;
  int tt = threadIdx.x >> 6, e = threadIdx.x & 63;
  __shared__ float hx[4][64];
  hx[tt][e] = bf2f(hbf[(size_t)(t0 + tt) * C_DIM + h * 64 + e]);
  __syncthreads();
  const float4* w4 = (const float4*)(vtmp + ((size_t)h * 64 + e) * 64);
  float s = 0.f;
  #pragma unroll
  for (int dd = 0; dd < 16; dd++) {
    float4 wv = w4[dd];
    s += hx[tt][dd*4+0]*wv.x + hx[tt][dd*4+1]*wv.y + hx[tt][dd*4+2]*wv.z + hx[tt][dd*4+3]*wv.w;
  }
  vt[((size_t)h * 64 + e) * T_SEQ + (t0 + tt)] = f2bf(s);
}

// x[t,h,e] += sum_d y[t,h,d]*proj_tmp[h,e,d]
__global__ void headproj_k(const float* __restrict__ y, const float* __restrict__ ptmp,
                           float* __restrict__ x) {
  int h = blockIdx.y, t0 = blockIdx.x * 4;
  int tt = threadIdx.x >> 6, e = threadIdx.x & 63;
  __shared__ float hx[4][64];
  hx[tt][e] = y[(size_t)(t0 + tt) * C_DIM + h * 64 + e];
  __syncthreads();
  const float4* w4 = (const float4*)(ptmp + ((size_t)h * 64 + e) * 64);
  float s = 0.f;
  #pragma unroll
  for (int dd = 0; dd < 16; dd++) {
    float4 wv = w4[dd];
    s += hx[tt][dd*4+0]*wv.x + hx[tt][dd*4+1]*wv.y + hx[tt][dd*4+2]*wv.z + hx[tt][dd*4+3]*wv.w;
  }
  x[(size_t)(t0 + tt) * C_DIM + h * 64 + e] += s;
}

// row softmax over 2048 (scores f32 chunk -> P bf16 full buffer)
__global__ void softmax_k(const float* __restrict__ S, u16* __restrict__ P, int qoff) {
  int rq = blockIdx.x, h = blockIdx.y;
  const float* Srow = S + ((size_t)h * QC + rq) * T_SEQ;
  u16* Prow = P + ((size_t)h * T_SEQ + qoff + rq) * T_SEQ;
  int tid = threadIdx.x, wid = tid >> 6, lane = tid & 63;
  float v[8];
  float mx = -3.4e38f;
  #pragma unroll
  for (int j = 0; j < 8; j++) { v[j] = Srow[tid + j * 256]; mx = fmaxf(mx, v[j]); }
  #pragma unroll
  for (int m = 32; m; m >>= 1) mx = fmaxf(mx, __shfl_xor(mx, m));
  __shared__ float redm[4], reds[4];
  if (lane == 0) redm[wid] = mx;
  __syncthreads();
  mx = fmaxf(fmaxf(redm[0], redm[1]), fmaxf(redm[2], redm[3]));
  float s = 0.f;
  #pragma unroll
  for (int j = 0; j < 8; j++) { v[j] = __expf(v[j] - mx); s += v[j]; }
  #pragma unroll
  for (int m = 32; m; m >>= 1) s += __shfl_xor(s, m);
  if (lane == 0) reds[wid] = s;
  __syncthreads();
  s = reds[0] + reds[1] + reds[2] + reds[3];
  float inv = 1.f / s;
  #pragma unroll
  for (int j = 0; j < 8; j++) Prow[tid + j * 256] = f2bf(v[j] * inv);
}

// ---------------- bf16 NT GEMM (MFMA 16x16x32), BK=64, XOR-swizzled LDS ------
// C[m,n] = sum_k A[m,k]*B[n,k]  (+ epilogue). Batched via blockIdx.z strides.
// EPI: 0=f32 store, 1=bias+bf16, 2=0.125*scale+alibi f32, 3=bias+gelu+bf16, 4=bias+resid+f32
template <int ROWS>
__device__ inline void stage_tile(u16* lds, const u16* __restrict__ g, int ld, int wid, int lane) {
  #pragma unroll
  for (int i = 0; i < ROWS / 32; i++) {
    int base = (i * 4 + wid) * 1024;           // wave-uniform LDS byte base
    int o = base + lane * 16;                  // this lane's linear dest
    int u = o ^ (((o >> 7) & 7) << 4);         // un-swizzled byte addr
    int row = u >> 7, colb = u & 127;
    const u16* src = g + (size_t)row * ld + (colb >> 1);
    __builtin_amdgcn_global_load_lds((const __attribute__((address_space(1))) void*)src,
                                     (__attribute__((address_space(3))) void*)(lds + base / 2),
                                     16, 0, 0);
  }
}

template <int BM, int BN, int WM, int WN, int EPI>
__global__ void gemm_nt(const u16* __restrict__ A, int lda, long long sA,
                        const u16* __restrict__ B, int ldb, long long sB,
                        void* __restrict__ C, int ldc, long long sC,
                        int K, const float* __restrict__ bias,
                        const float* __restrict__ resid, int ldr, int qoff) {
  constexpr int RM = BM / WM, RN = BN / WN;
  constexpr int MR = RM / 16, NR = RN / 16;
  __shared__ u16 lsA[BM * 64];
  __shared__ u16 lsB[BN * 64];
  int tid = threadIdx.x, wid = tid >> 6, lane = tid & 63;
  int wm = wid / WN, wn = wid % WN;
  int row0 = blockIdx.y * BM, col0 = blockIdx.x * BN;
  int z = blockIdx.z;
  const u16* Ab = A + (size_t)z * sA + (size_t)row0 * lda;
  const u16* Bb = B + (size_t)z * sB + (size_t)col0 * ldb;

  f32x4 acc[MR][NR];
  #pragma unroll
  for (int m = 0; m < MR; m++)
    #pragma unroll
    for (int n = 0; n < NR; n++) acc[m][n] = (f32x4){0.f, 0.f, 0.f, 0.f};

  for (int k0 = 0; k0 < K; k0 += 64) {
    stage_tile<BM>(lsA, Ab + k0, lda, wid, lane);
    stage_tile<BN>(lsB, Bb + k0, ldb, wid, lane);
    __syncthreads();   // compiler drains vmcnt here
    #pragma unroll
    for (int kk = 0; kk < 2; kk++) {
      bf16x8 af[MR], bfr[NR];
      #pragma unroll
      for (int m = 0; m < MR; m++) {
        int r = wm * RM + m * 16 + (lane & 15);
        int bofs = r * 128 + kk * 64 + ((lane >> 4) * 16);
        bofs ^= (r & 7) << 4;
        af[m] = *(const bf16x8*)((const char*)lsA + bofs);
      }
      #pragma unroll
      for (int n = 0; n < NR; n++) {
        int r = wn * RN + n * 16 + (lane & 15);
        int bofs = r * 128 + kk * 64 + ((lane >> 4) * 16);
        bofs ^= (r & 7) << 4;
        bfr[n] = *(const bf16x8*)((const char*)lsB + bofs);
      }
      #pragma unroll
      for (int m = 0; m < MR; m++)
        #pragma unroll
        for (int n = 0; n < NR; n++)
          acc[m][n] = __builtin_amdgcn_mfma_f32_16x16x32_bf16(af[m], bfr[n], acc[m][n], 0, 0, 0);
    }
    __syncthreads();
  }

  int rbase = row0 + wm * RM, cbase = col0 + wn * RN;
  float slope = 0.f;
  if constexpr (EPI == 2) slope = exp2f(-0.5f * (float)(z + 1));
  #pragma unroll
  for (int m = 0; m < MR; m++)
    #pragma unroll
    for (int n = 0; n < NR; n++)
      #pragma unroll
      for (int i = 0; i < 4; i++) {
        int gr = rbase + m * 16 + ((lane >> 4) * 4) + i;
        int gc = cbase + n * 16 + (lane & 15);
        float v = acc[m][n][i];
        if constexpr (EPI == 0) {
          ((float*)C)[(size_t)z * sC + (size_t)gr * ldc + gc] = v;
        } else if constexpr (EPI == 1) {
          v += bias[gc];
          ((u16*)C)[(size_t)gr * ldc + gc] = f2bf(v);
        } else if constexpr (EPI == 2) {
          v = v * 0.125f + slope * fminf((float)(gc - qoff - gr), 0.f);
          ((float*)C)[(size_t)z * sC + (size_t)gr * ldc + gc] = v;
        } else if constexpr (EPI == 3) {
          v += bias[gc];
          v = 0.5f * v * (1.f + erff(v * 0.70710678118654752f));
          ((u16*)C)[(size_t)gr * ldc + gc] = f2bf(v);
        } else {
          v += bias[gc] + resid[(size_t)gr * ldr + gc];
          ((float*)C)[(size_t)gr * ldc + gc] = v;
        }
      }
}

// ---------------- host launch ----------------
extern "C" void kernel_launch(void* const* d_in, const int* in_sizes, int n_in,
                              void* d_out, int out_size, void* d_ws, size_t ws_size,
                              hipStream_t stream) {
  (void)in_sizes; (void)n_in; (void)out_size; (void)d_ws; (void)ws_size;
  const int*   idx    = (const int*)d_in[0];
  const float* wte    = (const float*)d_in[1];
  const float* ln1w   = (const float*)d_in[2];
  const float* ln1b   = (const float*)d_in[3];
  const float* ln2w   = (const float*)d_in[4];
  const float* ln2b   = (const float*)d_in[5];
  const float* lnfw   = (const float*)d_in[6];
  const float* lnfb   = (const float*)d_in[7];
  const float* attw   = (const float*)d_in[8];
  const float* attb   = (const float*)d_in[9];
  const float* vtmp   = (const float*)d_in[10];
  const float* ptmp   = (const float*)d_in[11];
  const float* fcw    = (const float*)d_in[12];
  const float* fcb    = (const float*)d_in[13];
  const float* prjw   = (const float*)d_in[14];
  const float* prjb   = (const float*)d_in[15];
  float* out = (float*)d_out;

  unsigned char* ar = nullptr;
  hipGetSymbolAddress((void**)&ar, HIP_SYMBOL(g_arena));
  u16*   wtebf  = (u16*)(ar + OFF_WTEBF);
  u16*   attnbf = (u16*)(ar + OFF_ATTNBF);
  u16*   fcbf   = (u16*)(ar + OFF_FCBF);
  u16*   prjbf  = (u16*)(ar + OFF_PRJBF);
  float* x      = (float*)(ar + OFF_X);
  u16*   hbf    = (u16*)(ar + OFF_HBF);
  u16*   qkbf   = (u16*)(ar + OFF_QKBF);
  u16*   vt     = (u16*)(ar + OFF_VT);
  float* y      = (float*)(ar + OFF_Y);
  float* sc     = (float*)(ar + OFF_SC);
  u16*   pbf    = (u16*)(ar + OFF_PBF);
  u16*   fbf    = (u16*)(ar + OFF_FBF);

  // weight conversions fp32 -> bf16
  cvt_bf16_k<<<dim3((V_VOCAB * C_DIM / 4) / 256), 256, 0, stream>>>((const float4*)wte, (ushort4*)wtebf, V_VOCAB * C_DIM / 4);
  cvt_bf16_k<<<dim3((L_LAYERS * 2 * C_DIM * C_DIM / 4) / 256), 256, 0, stream>>>((const float4*)attw, (ushort4*)attnbf, L_LAYERS * 2 * C_DIM * C_DIM / 4);
  cvt_bf16_k<<<dim3((L_LAYERS * FF_DIM * C_DIM / 4) / 256), 256, 0, stream>>>((const float4*)fcw, (ushort4*)fcbf, L_LAYERS * FF_DIM * C_DIM / 4);
  cvt_bf16_k<<<dim3((L_LAYERS * C_DIM * FF_DIM / 4) / 256), 256, 0, stream>>>((const float4*)prjw, (ushort4*)prjbf, L_LAYERS * C_DIM * FF_DIM / 4);

  embed_k<<<dim3(T_SEQ), 256, 0, stream>>>(idx, (const float4*)wte, (float4*)x);

  for (int l = 0; l < L_LAYERS; l++) {
    symln_k<<<dim3(T_SEQ), 256, 0, stream>>>(x, ln1w + l * H_HEADS, ln1b + l * H_HEADS, hbf);
    // qk = LN(x) @ attn_w^T + attn_b  -> bf16
    gemm_nt<128, 128, 2, 2, 1><<<dim3(2 * C_DIM / 128, T_SEQ / 128, 1), 256, 0, stream>>>(
        hbf, C_DIM, 0, attnbf + (size_t)l * 2 * C_DIM * C_DIM, C_DIM, 0,
        qkbf, 2 * C_DIM, 0, C_DIM, attb + l * 2 * C_DIM, nullptr, 0, 0);
    vcompute_k<<<dim3(T_SEQ / 4, H_HEADS), 256, 0, stream>>>(hbf, vtmp + (size_t)l * H_HEADS * 64 * 64, vt);
    for (int qc = 0; qc < T_SEQ / QC; qc++) {
      // scores = 0.125 * Q Kt + alibi   (batched over heads)
      gemm_nt<128, 128, 2, 2, 2><<<dim3(T_SEQ / 128, QC / 128, H_HEADS), 256, 0, stream>>>(
          qkbf + (size_t)qc * QC * 2 * C_DIM, 2 * C_DIM, 64,
          qkbf + C_DIM, 2 * C_DIM, 64,
          sc, T_SEQ, (long long)QC * T_SEQ, 64, nullptr, nullptr, 0, qc * QC);
      softmax_k<<<dim3(QC, H_HEADS), 256, 0, stream>>>(sc, pbf, qc * QC);
    }
    // y[:, h*64:(h+1)*64] = P[h] @ Vt[h]^T  (batched over heads)
    gemm_nt<128, 64, 4, 1, 0><<<dim3(1, T_SEQ / 128, H_HEADS), 256, 0, stream>>>(
        pbf, T_SEQ, (long long)T_SEQ * T_SEQ, vt, T_SEQ, (long long)64 * T_SEQ,
        y, C_DIM, 64, T_SEQ, nullptr, nullptr, 0, 0);
    headproj_k<<<dim3(T_SEQ / 4, H_HEADS), 256, 0, stream>>>(y, ptmp + (size_t)l * H_HEADS * 64 * 64, x);
    symln_k<<<dim3(T_SEQ), 256, 0, stream>>>(x, ln2w + l * H_HEADS, ln2b + l * H_HEADS, hbf);
    // f = gelu(LN2(x) @ fc_w^T + fc_b) -> bf16
    gemm_nt<128, 128, 2, 2, 3><<<dim3(FF_DIM / 128, T_SEQ / 128, 1), 256, 0, stream>>>(
        hbf, C_DIM, 0, fcbf + (size_t)l * FF_DIM * C_DIM, C_DIM, 0,
        fbf, FF_DIM, 0, C_DIM, fcb + l * FF_DIM, nullptr, 0, 0);
    // x = x + f @ proj_w^T + proj_b
    gemm_nt<128, 128, 2, 2, 4><<<dim3(C_DIM / 128, T_SEQ / 128, 1), 256, 0, stream>>>(
        fbf, FF_DIM, 0, prjbf + (size_t)l * C_DIM * FF_DIM, FF_DIM, 0,
        x, C_DIM, 0, FF_DIM, prjb + l * C_DIM, x, C_DIM, 0);
  }
  symln_k<<<dim3(T_SEQ), 256, 0, stream>>>(x, lnfw, lnfb, hbf);
  // logits = LN_f(x) @ wte^T  (f32 out)
  gemm_nt<128, 128, 2, 2, 0><<<dim3(V_VOCAB / 128, T_SEQ / 128, 1), 256, 0, stream>>>(
      hbf, C_DIM, 0, wtebf, C_DIM, 0, out, V_VOCAB, 0, C_DIM, nullptr, nullptr, 0, 0);
}

// Round 2
// 914.646 us; speedup vs baseline: 1.3079x; 1.3079x over previous
//
#include <hip/hip_runtime.h>
#include <cstdint>
#include <cstddef>

// ---------------- problem constants ----------------
#define T_SEQ 2048
#define C_DIM 1024
#define H_HEADS 16
#define D_HEAD 64
#define FF_DIM 4096
#define V_VOCAB 32000
#define L_LAYERS 2

typedef unsigned short u16;
typedef short bf16x8 __attribute__((ext_vector_type(8)));
typedef float f32x4 __attribute__((ext_vector_type(4)));

__device__ inline u16 f2bf(float f) {
  unsigned u = __float_as_uint(f);
  u += 0x7fffu + ((u >> 16) & 1u);   // RNE
  return (u16)(u >> 16);
}
__device__ inline float bf2f(u16 h) { return __uint_as_float(((unsigned)h) << 16); }

// ---------------- device arena ----------------
#define OFF_WTEBF   0ULL                    // 32000*1024 bf16
#define OFF_ATTNBF  65536000ULL             // 2*2048*1024 bf16
#define OFF_FCBF    73924608ULL             // 2*4096*1024 bf16
#define OFF_PRJBF   90701824ULL             // 2*1024*4096 bf16
#define OFF_X       107479040ULL            // 2048*1024 f32 (residual stream)
#define OFF_HBF     115867648ULL            // 2048*1024 bf16 (LN out)
#define OFF_QKBF    120061952ULL            // 2048*2048 bf16 (q|k)
#define OFF_VT      128450560ULL            // 16*64*2048 bf16 (V^T per head)
#define OFF_Y       132644864ULL            // 2048*1024 f32 (attn out pre-proj)
#define OFF_FBF     141033472ULL            // 2048*4096 bf16 (gelu(fc) out)
#define ARENA_BYTES 157810688ULL

__device__ __align__(1024) unsigned char g_arena[ARENA_BYTES];

// ---------------- tiny kernels ----------------
__global__ void cvt_bf16_k(const float4* __restrict__ in, ushort4* __restrict__ out, int n4) {
  int i = blockIdx.x * 256 + threadIdx.x;
  if (i < n4) {
    float4 v = in[i];
    out[i] = make_ushort4(f2bf(v.x), f2bf(v.y), f2bf(v.z), f2bf(v.w));
  }
}

__global__ void embed_k(const int* __restrict__ idx, const float4* __restrict__ wte,
                        float4* __restrict__ x) {
  int t = blockIdx.x;
  int r = idx[t];
  x[(size_t)t * 256 + threadIdx.x] = wte[(size_t)r * 256 + threadIdx.x];
}

// per-(token, head) LayerNorm over 64 channels, scalar w/b per head; bf16 out
__global__ void symln_k(const float* __restrict__ x, const float* __restrict__ w,
                        const float* __restrict__ b, u16* __restrict__ out) {
  int t = blockIdx.x;
  int wv = threadIdx.x >> 6, lane = threadIdx.x & 63;
  #pragma unroll
  for (int hh = 0; hh < 4; hh++) {
    int h = wv * 4 + hh;
    float v = x[(size_t)t * C_DIM + h * 64 + lane];
    float s = v, s2 = v * v;
    #pragma unroll
    for (int m = 32; m; m >>= 1) { s += __shfl_xor(s, m); s2 += __shfl_xor(s2, m); }
    float mu = s * (1.f / 64.f);
    float var = s2 * (1.f / 64.f) - mu * mu;
    float n = (v - mu) * rsqrtf(var + 1e-5f) * w[h] + b[h];
    out[(size_t)t * C_DIM + h * 64 + lane] = f2bf(n);
  }
}

// v[t,h,e] = sum_d h_in[t,h,d]*v_tmp[h,e,d]  -> stored transposed vt[h][e][t] (bf16)
__global__ void vcompute_k(const u16* __restrict__ hbf, const float* __restrict__ vtmp,
                           u16* __restrict__ vt) {
  int h = blockIdx.y, t0 = blockIdx.x * 4;
  int tt = threadIdx.x >> 6, e = threadIdx.x & 63;
  __shared__ float hx[4][64];
  hx[tt][e] = bf2f(hbf[(size_t)(t0 + tt) * C_DIM + h * 64 + e]);
  __syncthreads();
  const float4* w4 = (const float4*)(vtmp + ((size_t)h * 64 + e) * 64);
  float s = 0.f;
  #pragma unroll
  for (int dd = 0; dd < 16; dd++) {
    float4 wv = w4[dd];
    s += hx[tt][dd*4+0]*wv.x + hx[tt][dd*4+1]*wv.y + hx[tt][dd*4+2]*wv.z + hx[tt][dd*4+3]*wv.w;
  }
  vt[((size_t)h * 64 + e) * T_SEQ + (t0 + tt)] = f2bf(s);
}

// x[t,h,e] += sum_d y[t,h,d]*proj_tmp[h,e,d]
__global__ void headproj_k(const float* __restrict__ y, const float* __restrict__ ptmp,
                           float* __restrict__ x) {
  int h = blockIdx.y, t0 = blockIdx.x * 4;
  int tt = threadIdx.x >> 6, e = threadIdx.x & 63;
  __shared__ float hx[4][64];
  hx[tt][e] = y[(size_t)(t0 + tt) * C_DIM + h * 64 + e];
  __syncthreads();
  const float4* w4 = (const float4*)(ptmp + ((size_t)h * 64 + e) * 64);
  float s = 0.f;
  #pragma unroll
  for (int dd = 0; dd < 16; dd++) {
    float4 wv = w4[dd];
    s += hx[tt][dd*4+0]*wv.x + hx[tt][dd*4+1]*wv.y + hx[tt][dd*4+2]*wv.z + hx[tt][dd*4+3]*wv.w;
  }
  x[(size_t)(t0 + tt) * C_DIM + h * 64 + e] += s;
}

// ---------------- generic swizzled global->LDS staging ----------------
// Stages NROWS rows of ROWBYTES bytes each; LDS holds them XOR-swizzled:
// swz(addr) = addr ^ (((addr/ROWBYTES)&7)<<4). Readers must apply same XOR.
template <int NROWS, int ROWBYTES, int WAVES>
__device__ inline void stage_rows(u16* lds, const u16* __restrict__ g, int ld,
                                  int wid, int lane) {
  constexpr int PASSES = (NROWS * ROWBYTES) / (WAVES * 1024);
  #pragma unroll
  for (int i = 0; i < PASSES; i++) {
    int base = (i * WAVES + wid) * 1024;          // wave-uniform LDS byte base
    int o = base + lane * 16;                     // this lane's linear dest
    int u = o ^ (((o / ROWBYTES) & 7) << 4);      // un-swizzled byte addr
    int row = u / ROWBYTES, colb = u % ROWBYTES;
    const u16* src = g + (size_t)row * ld + (colb >> 1);
    __builtin_amdgcn_global_load_lds((const __attribute__((address_space(1))) void*)src,
                                     (__attribute__((address_space(3))) void*)(lds + base / 2),
                                     16, 0, 0);
  }
}

// ---------------- flash attention (fused QK^T + ALiBi + softmax + PV) -------
// grid (T/64, H), 128 threads (2 waves). Each wave owns 32 query rows.
// K-tile: 128 keys. Q,K from qkbf [t][2048] (q cols h*64, k cols 1024+h*64).
// V^T from vt [h][d][t]. Output y [t][h*64+d] f32.
__global__ __launch_bounds__(128) void flash_k(const u16* __restrict__ qk,
                                               const u16* __restrict__ vt,
                                               float* __restrict__ y) {
  int h = blockIdx.y;
  int q0 = blockIdx.x * 64;
  int tid = threadIdx.x, wid = tid >> 6, lane = tid & 63;
  int g4 = lane >> 4, l15 = lane & 15;
  __shared__ u16 Kl[128 * 64];    // [key][d]   rowbytes=128, swizzled
  __shared__ u16 Vl[64 * 128];    // [d][key]   rowbytes=256, swizzled
  __shared__ u16 Pl[64 * 64];     // [qrow][key-half] rowbytes=128, swizzled
  float slope = exp2f(-0.5f * (float)(h + 1));

  // Q fragments (held in regs for the whole kernel)
  bf16x8 qf[2][2];
  const u16* qb = qk + (size_t)(q0 + wid * 32) * 2048 + h * 64;
  #pragma unroll
  for (int m = 0; m < 2; m++)
    #pragma unroll
    for (int kk = 0; kk < 2; kk++)
      qf[m][kk] = *(const bf16x8*)(qb + (size_t)(m * 16 + l15) * 2048 + kk * 32 + g4 * 8);

  float mrun[8], lrun[8];
  #pragma unroll
  for (int r = 0; r < 8; r++) { mrun[r] = -3.4e38f; lrun[r] = 0.f; }
  f32x4 oacc[2][4];
  #pragma unroll
  for (int m = 0; m < 2; m++)
    #pragma unroll
    for (int n = 0; n < 4; n++) oacc[m][n] = (f32x4){0.f, 0.f, 0.f, 0.f};

  const u16* kbase = qk + 1024 + h * 64;
  const u16* vbase = vt + (size_t)h * 64 * T_SEQ;

  for (int kt = 0; kt < T_SEQ / 128; kt++) {
    int k0 = kt * 128;
    stage_rows<128, 128, 2>(Kl, kbase + (size_t)k0 * 2048, 2048, wid, lane);
    stage_rows<64, 256, 2>(Vl, vbase + k0, T_SEQ, wid, lane);
    __syncthreads();

    // S = 0.125 * Q K^T + alibi  (wave computes its 32x128 block)
    f32x4 s[2][8];
    #pragma unroll
    for (int m = 0; m < 2; m++)
      #pragma unroll
      for (int n = 0; n < 8; n++) s[m][n] = (f32x4){0.f, 0.f, 0.f, 0.f};
    #pragma unroll
    for (int kk = 0; kk < 2; kk++) {
      bf16x8 kf[8];
      #pragma unroll
      for (int n = 0; n < 8; n++) {
        int r = n * 16 + l15;
        int b = (r * 128 + kk * 64 + g4 * 16) ^ ((r & 7) << 4);
        kf[n] = *(const bf16x8*)((const char*)Kl + b);
      }
      #pragma unroll
      for (int m = 0; m < 2; m++)
        #pragma unroll
        for (int n = 0; n < 8; n++)
          s[m][n] = __builtin_amdgcn_mfma_f32_16x16x32_bf16(qf[m][kk], kf[n], s[m][n], 0, 0, 0);
    }

    // online softmax (rows owned per lane: q = q0+wid*32+m*16+g4*4+i)
    #pragma unroll
    for (int m = 0; m < 2; m++)
      #pragma unroll
      for (int i = 0; i < 4; i++) {
        int iq = q0 + wid * 32 + m * 16 + g4 * 4 + i;
        float mx = -3.4e38f;
        #pragma unroll
        for (int n = 0; n < 8; n++) {
          int j = k0 + n * 16 + l15;
          float v = s[m][n][i] * 0.125f + slope * fminf((float)(j - iq), 0.f);
          s[m][n][i] = v;
          mx = fmaxf(mx, v);
        }
        #pragma unroll
        for (int msk = 8; msk; msk >>= 1) mx = fmaxf(mx, __shfl_xor(mx, msk));
        int r = m * 4 + i;
        float mnew = fmaxf(mrun[r], mx);
        float scale = __expf(mrun[r] - mnew);
        float sum = 0.f;
        #pragma unroll
        for (int n = 0; n < 8; n++) {
          float p = __expf(s[m][n][i] - mnew);
          s[m][n][i] = p;
          sum += p;
        }
        #pragma unroll
        for (int msk = 8; msk; msk >>= 1) sum += __shfl_xor(sum, msk);
        lrun[r] = lrun[r] * scale + sum;
        mrun[r] = mnew;
        #pragma unroll
        for (int n = 0; n < 4; n++) oacc[m][n][i] *= scale;
      }

    // PV in two 64-key halves through Pl (wave-private rows, no barrier needed)
    #pragma unroll
    for (int half = 0; half < 2; half++) {
      #pragma unroll
      for (int m = 0; m < 2; m++)
        #pragma unroll
        for (int nl = 0; nl < 4; nl++) {
          int n = half * 4 + nl;
          #pragma unroll
          for (int i = 0; i < 4; i++) {
            int pr = wid * 32 + m * 16 + g4 * 4 + i;
            int b = (pr * 128 + nl * 32 + l15 * 2) ^ ((pr & 7) << 4);
            *(u16*)((char*)Pl + b) = f2bf(s[m][n][i]);
          }
        }
      #pragma unroll
      for (int kkl = 0; kkl < 2; kkl++) {
        bf16x8 pa[2], vf[4];
        #pragma unroll
        for (int m = 0; m < 2; m++) {
          int pr = wid * 32 + m * 16 + l15;
          int b = (pr * 128 + kkl * 64 + g4 * 16) ^ ((pr & 7) << 4);
          pa[m] = *(const bf16x8*)((const char*)Pl + b);
        }
        #pragma unroll
        for (int n = 0; n < 4; n++) {
          int d = n * 16 + l15;
          int b = (d * 256 + half * 128 + kkl * 64 + g4 * 16) ^ ((d & 7) << 4);
          vf[n] = *(const bf16x8*)((const char*)Vl + b);
        }
        #pragma unroll
        for (int m = 0; m < 2; m++)
          #pragma unroll
          for (int n = 0; n < 4; n++)
            oacc[m][n] = __builtin_amdgcn_mfma_f32_16x16x32_bf16(pa[m], vf[n], oacc[m][n], 0, 0, 0);
      }
    }
    __syncthreads();
  }

  // epilogue: O /= l ; write y
  float inv[8];
  #pragma unroll
  for (int r = 0; r < 8; r++) inv[r] = 1.f / lrun[r];
  float* yb = y + (size_t)(q0 + wid * 32) * C_DIM + h * 64;
  #pragma unroll
  for (int m = 0; m < 2; m++)
    #pragma unroll
    for (int n = 0; n < 4; n++)
      #pragma unroll
      for (int i = 0; i < 4; i++)
        yb[(size_t)(m * 16 + g4 * 4 + i) * C_DIM + n * 16 + l15] = oacc[m][n][i] * inv[m * 4 + i];
}

// ---------------- bf16 NT GEMM (MFMA 16x16x32), BK=64, XOR-swizzled LDS ------
// C[m,n] = sum_k A[m,k]*B[n,k]  (+ epilogue). Batched via blockIdx.z strides.
// EPI: 0=f32 store, 1=bias+bf16, 3=bias+gelu+bf16, 4=bias+resid+f32
// MT>0: 1D grid, M-fast work order + bijective XCD chunking (nwg%8==0).
template <int BM, int BN, int WM, int WN, int EPI, int MT>
__global__ void gemm_nt(const u16* __restrict__ A, int lda, long long sA,
                        const u16* __restrict__ B, int ldb, long long sB,
                        void* __restrict__ C, int ldc, long long sC,
                        int K, const float* __restrict__ bias,
                        const float* __restrict__ resid, int ldr) {
  constexpr int RM = BM / WM, RN = BN / WN;
  constexpr int MR = RM / 16, NR = RN / 16;
  __shared__ u16 lsA[BM * 64];
  __shared__ u16 lsB[BN * 64];
  int tid = threadIdx.x, wid = tid >> 6, lane = tid & 63;
  int wm = wid / WN, wn = wid % WN;
  int bx, by, z;
  if constexpr (MT > 0) {
    int nwg = gridDim.x;
    int lin = blockIdx.x;
    int chunk = nwg >> 3;
    int w = (lin & 7) * chunk + (lin >> 3);   // XCD gets contiguous chunk
    by = w % MT;                              // M tile (fast -> B-panel reuse)
    bx = w / MT;
    z = 0;
  } else {
    bx = blockIdx.x; by = blockIdx.y; z = blockIdx.z;
  }
  int row0 = by * BM, col0 = bx * BN;
  const u16* Ab = A + (size_t)z * sA + (size_t)row0 * lda;
  const u16* Bb = B + (size_t)z * sB + (size_t)col0 * ldb;

  f32x4 acc[MR][NR];
  #pragma unroll
  for (int m = 0; m < MR; m++)
    #pragma unroll
    for (int n = 0; n < NR; n++) acc[m][n] = (f32x4){0.f, 0.f, 0.f, 0.f};

  for (int k0 = 0; k0 < K; k0 += 64) {
    stage_rows<BM, 128, 4>(lsA, Ab + k0, lda, wid, lane);
    stage_rows<BN, 128, 4>(lsB, Bb + k0, ldb, wid, lane);
    __syncthreads();
    #pragma unroll
    for (int kk = 0; kk < 2; kk++) {
      bf16x8 af[MR], bfr[NR];
      #pragma unroll
      for (int m = 0; m < MR; m++) {
        int r = wm * RM + m * 16 + (lane & 15);
        int bofs = (r * 128 + kk * 64 + ((lane >> 4) * 16)) ^ ((r & 7) << 4);
        af[m] = *(const bf16x8*)((const char*)lsA + bofs);
      }
      #pragma unroll
      for (int n = 0; n < NR; n++) {
        int r = wn * RN + n * 16 + (lane & 15);
        int bofs = (r * 128 + kk * 64 + ((lane >> 4) * 16)) ^ ((r & 7) << 4);
        bfr[n] = *(const bf16x8*)((const char*)lsB + bofs);
      }
      #pragma unroll
      for (int m = 0; m < MR; m++)
        #pragma unroll
        for (int n = 0; n < NR; n++)
          acc[m][n] = __builtin_amdgcn_mfma_f32_16x16x32_bf16(af[m], bfr[n], acc[m][n], 0, 0, 0);
    }
    __syncthreads();
  }

  int rbase = row0 + wm * RM, cbase = col0 + wn * RN;
  #pragma unroll
  for (int m = 0; m < MR; m++)
    #pragma unroll
    for (int n = 0; n < NR; n++)
      #pragma unroll
      for (int i = 0; i < 4; i++) {
        int gr = rbase + m * 16 + ((lane >> 4) * 4) + i;
        int gc = cbase + n * 16 + (lane & 15);
        float v = acc[m][n][i];
        if constexpr (EPI == 0) {
          ((float*)C)[(size_t)z * sC + (size_t)gr * ldc + gc] = v;
        } else if constexpr (EPI == 1) {
          v += bias[gc];
          ((u16*)C)[(size_t)gr * ldc + gc] = f2bf(v);
        } else if constexpr (EPI == 3) {
          v += bias[gc];
          v = 0.5f * v * (1.f + erff(v * 0.70710678118654752f));
          ((u16*)C)[(size_t)gr * ldc + gc] = f2bf(v);
        } else {
          v += bias[gc] + resid[(size_t)gr * ldr + gc];
          ((float*)C)[(size_t)gr * ldc + gc] = v;
        }
      }
}

// ---------------- host launch ----------------
extern "C" void kernel_launch(void* const* d_in, const int* in_sizes, int n_in,
                              void* d_out, int out_size, void* d_ws, size_t ws_size,
                              hipStream_t stream) {
  (void)in_sizes; (void)n_in; (void)out_size; (void)d_ws; (void)ws_size;
  const int*   idx    = (const int*)d_in[0];
  const float* wte    = (const float*)d_in[1];
  const float* ln1w   = (const float*)d_in[2];
  const float* ln1b   = (const float*)d_in[3];
  const float* ln2w   = (const float*)d_in[4];
  const float* ln2b   = (const float*)d_in[5];
  const float* lnfw   = (const float*)d_in[6];
  const float* lnfb   = (const float*)d_in[7];
  const float* attw   = (const float*)d_in[8];
  const float* attb   = (const float*)d_in[9];
  const float* vtmp   = (const float*)d_in[10];
  const float* ptmp   = (const float*)d_in[11];
  const float* fcw    = (const float*)d_in[12];
  const float* fcb    = (const float*)d_in[13];
  const float* prjw   = (const float*)d_in[14];
  const float* prjb   = (const float*)d_in[15];
  float* out = (float*)d_out;

  unsigned char* ar = nullptr;
  hipGetSymbolAddress((void**)&ar, HIP_SYMBOL(g_arena));
  u16*   wtebf  = (u16*)(ar + OFF_WTEBF);
  u16*   attnbf = (u16*)(ar + OFF_ATTNBF);
  u16*   fcbf   = (u16*)(ar + OFF_FCBF);
  u16*   prjbf  = (u16*)(ar + OFF_PRJBF);
  float* x      = (float*)(ar + OFF_X);
  u16*   hbf    = (u16*)(ar + OFF_HBF);
  u16*   qkbf   = (u16*)(ar + OFF_QKBF);
  u16*   vt     = (u16*)(ar + OFF_VT);
  float* y      = (float*)(ar + OFF_Y);
  u16*   fbf    = (u16*)(ar + OFF_FBF);

  // weight conversions fp32 -> bf16
  cvt_bf16_k<<<dim3((V_VOCAB * C_DIM / 4) / 256), 256, 0, stream>>>((const float4*)wte, (ushort4*)wtebf, V_VOCAB * C_DIM / 4);
  cvt_bf16_k<<<dim3((L_LAYERS * 2 * C_DIM * C_DIM / 4) / 256), 256, 0, stream>>>((const float4*)attw, (ushort4*)attnbf, L_LAYERS * 2 * C_DIM * C_DIM / 4);
  cvt_bf16_k<<<dim3((L_LAYERS * FF_DIM * C_DIM / 4) / 256), 256, 0, stream>>>((const float4*)fcw, (ushort4*)fcbf, L_LAYERS * FF_DIM * C_DIM / 4);
  cvt_bf16_k<<<dim3((L_LAYERS * C_DIM * FF_DIM / 4) / 256), 256, 0, stream>>>((const float4*)prjw, (ushort4*)prjbf, L_LAYERS * C_DIM * FF_DIM / 4);

  embed_k<<<dim3(T_SEQ), 256, 0, stream>>>(idx, (const float4*)wte, (float4*)x);

  for (int l = 0; l < L_LAYERS; l++) {
    symln_k<<<dim3(T_SEQ), 256, 0, stream>>>(x, ln1w + l * H_HEADS, ln1b + l * H_HEADS, hbf);
    // qk = LN(x) @ attn_w^T + attn_b  -> bf16   (1D grid, M-fast, 256 blocks)
    gemm_nt<128, 128, 2, 2, 1, 16><<<dim3((2 * C_DIM / 128) * (T_SEQ / 128)), 256, 0, stream>>>(
        hbf, C_DIM, 0, attnbf + (size_t)l * 2 * C_DIM * C_DIM, C_DIM, 0,
        qkbf, 2 * C_DIM, 0, C_DIM, attb + l * 2 * C_DIM, nullptr, 0);
    vcompute_k<<<dim3(T_SEQ / 4, H_HEADS), 256, 0, stream>>>(hbf, vtmp + (size_t)l * H_HEADS * 64 * 64, vt);
    // fused flash attention -> y
    flash_k<<<dim3(T_SEQ / 64, H_HEADS), 128, 0, stream>>>(qkbf, vt, y);
    headproj_k<<<dim3(T_SEQ / 4, H_HEADS), 256, 0, stream>>>(y, ptmp + (size_t)l * H_HEADS * 64 * 64, x);
    symln_k<<<dim3(T_SEQ), 256, 0, stream>>>(x, ln2w + l * H_HEADS, ln2b + l * H_HEADS, hbf);
    // f = gelu(LN2(x) @ fc_w^T + fc_b) -> bf16  (512 blocks)
    gemm_nt<128, 128, 2, 2, 3, 16><<<dim3((FF_DIM / 128) * (T_SEQ / 128)), 256, 0, stream>>>(
        hbf, C_DIM, 0, fcbf + (size_t)l * FF_DIM * C_DIM, C_DIM, 0,
        fbf, FF_DIM, 0, C_DIM, fcb + l * FF_DIM, nullptr, 0);
    // x = x + f @ proj_w^T + proj_b  (128 blocks)
    gemm_nt<128, 128, 2, 2, 4, 16><<<dim3((C_DIM / 128) * (T_SEQ / 128)), 256, 0, stream>>>(
        fbf, FF_DIM, 0, prjbf + (size_t)l * C_DIM * FF_DIM, FF_DIM, 0,
        x, C_DIM, 0, FF_DIM, prjb + l * C_DIM, x, C_DIM);
  }
  symln_k<<<dim3(T_SEQ), 256, 0, stream>>>(x, lnfw, lnfb, hbf);
  // logits = LN_f(x) @ wte^T  (f32 out; 4000 blocks, M-fast + XCD chunking)
  gemm_nt<128, 128, 2, 2, 0, 16><<<dim3((V_VOCAB / 128) * (T_SEQ / 128)), 256, 0, stream>>>(
      hbf, C_DIM, 0, wtebf, C_DIM, 0, out, V_VOCAB, 0, C_DIM, nullptr, nullptr, 0);
}

// Round 3
// 838.271 us; speedup vs baseline: 1.4271x; 1.0911x over previous
//
#include <hip/hip_runtime.h>
#include <cstdint>
#include <cstddef>

// ---------------- problem constants ----------------
#define T_SEQ 2048
#define C_DIM 1024
#define H_HEADS 16
#define D_HEAD 64
#define FF_DIM 4096
#define V_VOCAB 32000
#define L_LAYERS 2

typedef unsigned short u16;
typedef short bf16x8 __attribute__((ext_vector_type(8)));
typedef float f32x4 __attribute__((ext_vector_type(4)));

__device__ inline u16 f2bf(float f) {
  unsigned u = __float_as_uint(f);
  u += 0x7fffu + ((u >> 16) & 1u);   // RNE
  return (u16)(u >> 16);
}
__device__ inline float bf2f(u16 h) { return __uint_as_float(((unsigned)h) << 16); }

// ---------------- device arena ----------------
#define OFF_WTEBF   0ULL                    // 32000*1024 bf16
#define OFF_ATTNBF  65536000ULL             // 2*2048*1024 bf16
#define OFF_FCBF    73924608ULL             // 2*4096*1024 bf16
#define OFF_PRJBF   90701824ULL             // 2*1024*4096 bf16
#define OFF_X       107479040ULL            // 2048*1024 f32 (residual stream)
#define OFF_HBF     115867648ULL            // 2048*1024 bf16 (LN out)
#define OFF_QKBF    120061952ULL            // 2048*2048 bf16 (q|k)
#define OFF_VT      128450560ULL            // 16*64*2048 bf16 (V^T per head)
#define OFF_Y       132644864ULL            // 2048*1024 f32 (attn out pre-proj)
#define OFF_FBF     141033472ULL            // 2048*4096 bf16 (gelu(fc) out)
#define ARENA_BYTES 157810688ULL

__device__ __align__(1024) unsigned char g_arena[ARENA_BYTES];

// ---------------- tiny kernels ----------------
__global__ void cvt_bf16_k(const float4* __restrict__ in, ushort4* __restrict__ out, int n4) {
  int i = blockIdx.x * 256 + threadIdx.x;
  if (i < n4) {
    float4 v = in[i];
    out[i] = make_ushort4(f2bf(v.x), f2bf(v.y), f2bf(v.z), f2bf(v.w));
  }
}

__global__ void embed_k(const int* __restrict__ idx, const float4* __restrict__ wte,
                        float4* __restrict__ x) {
  int t = blockIdx.x;
  int r = idx[t];
  x[(size_t)t * 256 + threadIdx.x] = wte[(size_t)r * 256 + threadIdx.x];
}

// per-(token, head) LayerNorm over 64 channels, scalar w/b per head; bf16 out
__global__ void symln_k(const float* __restrict__ x, const float* __restrict__ w,
                        const float* __restrict__ b, u16* __restrict__ out) {
  int t = blockIdx.x;
  int wv = threadIdx.x >> 6, lane = threadIdx.x & 63;
  #pragma unroll
  for (int hh = 0; hh < 4; hh++) {
    int h = wv * 4 + hh;
    float v = x[(size_t)t * C_DIM + h * 64 + lane];
    float s = v, s2 = v * v;
    #pragma unroll
    for (int m = 32; m; m >>= 1) { s += __shfl_xor(s, m); s2 += __shfl_xor(s2, m); }
    float mu = s * (1.f / 64.f);
    float var = s2 * (1.f / 64.f) - mu * mu;
    float n = (v - mu) * rsqrtf(var + 1e-5f) * w[h] + b[h];
    out[(size_t)t * C_DIM + h * 64 + lane] = f2bf(n);
  }
}

// v[t,h,e] = sum_d h_in[t,h,d]*v_tmp[h,e,d]  -> stored transposed vt[h][e][t] (bf16)
__global__ void vcompute_k(const u16* __restrict__ hbf, const float* __restrict__ vtmp,
                           u16* __restrict__ vt) {
  int h = blockIdx.y, t0 = blockIdx.x * 4;
  int tt = threadIdx.x >> 6, e = threadIdx.x & 63;
  __shared__ float hx[4][64];
  hx[tt][e] = bf2f(hbf[(size_t)(t0 + tt) * C_DIM + h * 64 + e]);
  __syncthreads();
  const float4* w4 = (const float4*)(vtmp + ((size_t)h * 64 + e) * 64);
  float s = 0.f;
  #pragma unroll
  for (int dd = 0; dd < 16; dd++) {
    float4 wv = w4[dd];
    s += hx[tt][dd*4+0]*wv.x + hx[tt][dd*4+1]*wv.y + hx[tt][dd*4+2]*wv.z + hx[tt][dd*4+3]*wv.w;
  }
  vt[((size_t)h * 64 + e) * T_SEQ + (t0 + tt)] = f2bf(s);
}

// x[t,h,e] += sum_d y[t,h,d]*proj_tmp[h,e,d]
__global__ void headproj_k(const float* __restrict__ y, const float* __restrict__ ptmp,
                           float* __restrict__ x) {
  int h = blockIdx.y, t0 = blockIdx.x * 4;
  int tt = threadIdx.x >> 6, e = threadIdx.x & 63;
  __shared__ float hx[4][64];
  hx[tt][e] = y[(size_t)(t0 + tt) * C_DIM + h * 64 + e];
  __syncthreads();
  const float4* w4 = (const float4*)(ptmp + ((size_t)h * 64 + e) * 64);
  float s = 0.f;
  #pragma unroll
  for (int dd = 0; dd < 16; dd++) {
    float4 wv = w4[dd];
    s += hx[tt][dd*4+0]*wv.x + hx[tt][dd*4+1]*wv.y + hx[tt][dd*4+2]*wv.z + hx[tt][dd*4+3]*wv.w;
  }
  x[(size_t)(t0 + tt) * C_DIM + h * 64 + e] += s;
}

// ---------------- generic swizzled global->LDS staging ----------------
// Stages NROWS rows of ROWBYTES bytes each; LDS holds them XOR-swizzled:
// swz(addr) = addr ^ (((addr/ROWBYTES)&7)<<4). Readers must apply same XOR.
template <int NROWS, int ROWBYTES, int WAVES>
__device__ inline void stage_rows(u16* lds, const u16* __restrict__ g, int ld,
                                  int wid, int lane) {
  constexpr int PASSES = (NROWS * ROWBYTES) / (WAVES * 1024);
  #pragma unroll
  for (int i = 0; i < PASSES; i++) {
    int base = (i * WAVES + wid) * 1024;          // wave-uniform LDS byte base
    int o = base + lane * 16;                     // this lane's linear dest
    int u = o ^ (((o / ROWBYTES) & 7) << 4);      // un-swizzled byte addr
    int row = u / ROWBYTES, colb = u % ROWBYTES;
    const u16* src = g + (size_t)row * ld + (colb >> 1);
    __builtin_amdgcn_global_load_lds((const __attribute__((address_space(1))) void*)src,
                                     (__attribute__((address_space(3))) void*)(lds + base / 2),
                                     16, 0, 0);
  }
}

// ---------------- flash attention v2 --------------------------------------
// grid (T/64, H), 256 threads (4 waves), 16 q-rows per wave.
// Fixed-max softmax (scores bounded ~|3|): P = exp(s - 8), no in-loop reduces.
// l accumulated per-lane, reduced once at the end.
__global__ __launch_bounds__(256) void flash_k(const u16* __restrict__ qk,
                                               const u16* __restrict__ vt,
                                               float* __restrict__ y) {
  int h = blockIdx.y;
  int q0 = blockIdx.x * 64;
  int tid = threadIdx.x, wid = tid >> 6, lane = tid & 63;
  int g4 = lane >> 4, l15 = lane & 15;
  __shared__ u16 Kl[128 * 64];    // [key][d]    rowbytes 128, swizzled
  __shared__ u16 Vl[64 * 128];    // [d][key]    rowbytes 256, swizzled
  __shared__ u16 Pl[64 * 128];    // [qrow][key] rowbytes 256, wave-private rows
  float slope = exp2f(-0.5f * (float)(h + 1));

  // Q fragments for this wave's 16 rows (held in regs for whole kernel)
  bf16x8 qf[2];
  const u16* qb = qk + (size_t)(q0 + wid * 16) * 2048 + h * 64;
  #pragma unroll
  for (int kk = 0; kk < 2; kk++)
    qf[kk] = *(const bf16x8*)(qb + (size_t)l15 * 2048 + kk * 32 + g4 * 8);

  f32x4 lsum = (f32x4){0.f, 0.f, 0.f, 0.f};
  f32x4 oacc[4];
  #pragma unroll
  for (int n = 0; n < 4; n++) oacc[n] = (f32x4){0.f, 0.f, 0.f, 0.f};

  const u16* kbase = qk + 1024 + h * 64;
  const u16* vbase = vt + (size_t)h * 64 * T_SEQ;

  for (int kt = 0; kt < T_SEQ / 128; kt++) {
    int k0 = kt * 128;
    stage_rows<128, 128, 4>(Kl, kbase + (size_t)k0 * 2048, 2048, wid, lane);
    stage_rows<64, 256, 4>(Vl, vbase + k0, T_SEQ, wid, lane);
    __syncthreads();

    // S = Q K^T  (wave computes its 16x128 block)
    f32x4 s[8];
    #pragma unroll
    for (int n = 0; n < 8; n++) s[n] = (f32x4){0.f, 0.f, 0.f, 0.f};
    #pragma unroll
    for (int kk = 0; kk < 2; kk++) {
      #pragma unroll
      for (int n = 0; n < 8; n++) {
        int r = n * 16 + l15;
        int b = (r * 128 + kk * 64 + g4 * 16) ^ ((r & 7) << 4);
        bf16x8 kf = *(const bf16x8*)((const char*)Kl + b);
        s[n] = __builtin_amdgcn_mfma_f32_16x16x32_bf16(qf[kk], kf, s[n], 0, 0, 0);
      }
    }

    // alibi + exp(s - 8); accumulate per-lane l; write P to LDS (wave-private)
    int iq = q0 + wid * 16 + g4 * 4;
    #pragma unroll
    for (int n = 0; n < 8; n++) {
      int j = k0 + n * 16 + l15;
      #pragma unroll
      for (int i = 0; i < 4; i++) {
        float v = s[n][i] * 0.125f + slope * fminf((float)(j - (iq + i)), 0.f);
        float p = __expf(v - 8.f);
        lsum[i] += p;
        int pr = wid * 16 + g4 * 4 + i;
        int b = (pr * 256 + (n * 16 + l15) * 2) ^ ((pr & 7) << 4);
        *(u16*)((char*)Pl + b) = f2bf(p);
      }
    }

    // O += P V   (A = P rows q, B = V^T rows d)
    #pragma unroll
    for (int kk = 0; kk < 4; kk++) {
      int pr = wid * 16 + l15;
      int pb = (pr * 256 + kk * 64 + g4 * 16) ^ ((pr & 7) << 4);
      bf16x8 pa = *(const bf16x8*)((const char*)Pl + pb);
      #pragma unroll
      for (int n = 0; n < 4; n++) {
        int d = n * 16 + l15;
        int vb = (d * 256 + kk * 64 + g4 * 16) ^ ((d & 7) << 4);
        bf16x8 vf = *(const bf16x8*)((const char*)Vl + vb);
        oacc[n] = __builtin_amdgcn_mfma_f32_16x16x32_bf16(pa, vf, oacc[n], 0, 0, 0);
      }
    }
    __syncthreads();
  }

  // reduce l across the 16-lane column groups (rows live in g4 groups)
  #pragma unroll
  for (int i = 0; i < 4; i++) {
    float v = lsum[i];
    #pragma unroll
    for (int msk = 1; msk <= 8; msk <<= 1) v += __shfl_xor(v, msk);
    lsum[i] = v;
  }
  float* yb = y + (size_t)(q0 + wid * 16) * C_DIM + h * 64;
  #pragma unroll
  for (int n = 0; n < 4; n++)
    #pragma unroll
    for (int i = 0; i < 4; i++)
      yb[(size_t)(g4 * 4 + i) * C_DIM + n * 16 + l15] = oacc[n][i] / lsum[i];
}

// ---------------- bf16 NT GEMM (MFMA 16x16x32), BK=64, XOR-swizzled LDS ------
// C[m,n] = sum_k A[m,k]*B[n,k]  (+ epilogue).
// EPI: 0=f32 nontemporal store, 1=bias+bf16, 3=bias+gelu+bf16, 4=bias+resid+f32
// MT>0: 1D grid, M-fast work order + bijective XCD chunking (nwg%8==0).
template <int BM, int BN, int WM, int WN, int EPI, int MT>
__global__ void gemm_nt(const u16* __restrict__ A, int lda,
                        const u16* __restrict__ B, int ldb,
                        void* __restrict__ C, int ldc,
                        int K, const float* __restrict__ bias,
                        const float* __restrict__ resid, int ldr) {
  constexpr int RM = BM / WM, RN = BN / WN;
  constexpr int MR = RM / 16, NR = RN / 16;
  __shared__ u16 lsA[BM * 64];
  __shared__ u16 lsB[BN * 64];
  int tid = threadIdx.x, wid = tid >> 6, lane = tid & 63;
  int wm = wid / WN, wn = wid % WN;
  int bx, by;
  {
    int nwg = gridDim.x;
    int lin = blockIdx.x;
    int chunk = nwg >> 3;
    int w = (lin & 7) * chunk + (lin >> 3);   // XCD gets contiguous chunk
    by = w % MT;                              // M tile (fast -> B-panel reuse)
    bx = w / MT;
  }
  int row0 = by * BM, col0 = bx * BN;
  const u16* Ab = A + (size_t)row0 * lda;
  const u16* Bb = B + (size_t)col0 * ldb;

  f32x4 acc[MR][NR];
  #pragma unroll
  for (int m = 0; m < MR; m++)
    #pragma unroll
    for (int n = 0; n < NR; n++) acc[m][n] = (f32x4){0.f, 0.f, 0.f, 0.f};

  for (int k0 = 0; k0 < K; k0 += 64) {
    stage_rows<BM, 128, 4>(lsA, Ab + k0, lda, wid, lane);
    stage_rows<BN, 128, 4>(lsB, Bb + k0, ldb, wid, lane);
    __syncthreads();
    #pragma unroll
    for (int kk = 0; kk < 2; kk++) {
      bf16x8 af[MR], bfr[NR];
      #pragma unroll
      for (int m = 0; m < MR; m++) {
        int r = wm * RM + m * 16 + (lane & 15);
        int bofs = (r * 128 + kk * 64 + ((lane >> 4) * 16)) ^ ((r & 7) << 4);
        af[m] = *(const bf16x8*)((const char*)lsA + bofs);
      }
      #pragma unroll
      for (int n = 0; n < NR; n++) {
        int r = wn * RN + n * 16 + (lane & 15);
        int bofs = (r * 128 + kk * 64 + ((lane >> 4) * 16)) ^ ((r & 7) << 4);
        bfr[n] = *(const bf16x8*)((const char*)lsB + bofs);
      }
      #pragma unroll
      for (int m = 0; m < MR; m++)
        #pragma unroll
        for (int n = 0; n < NR; n++)
          acc[m][n] = __builtin_amdgcn_mfma_f32_16x16x32_bf16(af[m], bfr[n], acc[m][n], 0, 0, 0);
    }
    __syncthreads();
  }

  int rbase = row0 + wm * RM, cbase = col0 + wn * RN;
  #pragma unroll
  for (int m = 0; m < MR; m++)
    #pragma unroll
    for (int n = 0; n < NR; n++)
      #pragma unroll
      for (int i = 0; i < 4; i++) {
        int gr = rbase + m * 16 + ((lane >> 4) * 4) + i;
        int gc = cbase + n * 16 + (lane & 15);
        float v = acc[m][n][i];
        if constexpr (EPI == 0) {
          __builtin_nontemporal_store(v, &((float*)C)[(size_t)gr * ldc + gc]);
        } else if constexpr (EPI == 1) {
          v += bias[gc];
          ((u16*)C)[(size_t)gr * ldc + gc] = f2bf(v);
        } else if constexpr (EPI == 3) {
          v += bias[gc];
          v = 0.5f * v * (1.f + erff(v * 0.70710678118654752f));
          ((u16*)C)[(size_t)gr * ldc + gc] = f2bf(v);
        } else {
          v += bias[gc] + resid[(size_t)gr * ldr + gc];
          ((float*)C)[(size_t)gr * ldc + gc] = v;
        }
      }
}

// ---------------- host launch ----------------
extern "C" void kernel_launch(void* const* d_in, const int* in_sizes, int n_in,
                              void* d_out, int out_size, void* d_ws, size_t ws_size,
                              hipStream_t stream) {
  (void)in_sizes; (void)n_in; (void)out_size; (void)d_ws; (void)ws_size;
  const int*   idx    = (const int*)d_in[0];
  const float* wte    = (const float*)d_in[1];
  const float* ln1w   = (const float*)d_in[2];
  const float* ln1b   = (const float*)d_in[3];
  const float* ln2w   = (const float*)d_in[4];
  const float* ln2b   = (const float*)d_in[5];
  const float* lnfw   = (const float*)d_in[6];
  const float* lnfb   = (const float*)d_in[7];
  const float* attw   = (const float*)d_in[8];
  const float* attb   = (const float*)d_in[9];
  const float* vtmp   = (const float*)d_in[10];
  const float* ptmp   = (const float*)d_in[11];
  const float* fcw    = (const float*)d_in[12];
  const float* fcb    = (const float*)d_in[13];
  const float* prjw   = (const float*)d_in[14];
  const float* prjb   = (const float*)d_in[15];
  float* out = (float*)d_out;

  unsigned char* ar = nullptr;
  hipGetSymbolAddress((void**)&ar, HIP_SYMBOL(g_arena));
  u16*   wtebf  = (u16*)(ar + OFF_WTEBF);
  u16*   attnbf = (u16*)(ar + OFF_ATTNBF);
  u16*   fcbf   = (u16*)(ar + OFF_FCBF);
  u16*   prjbf  = (u16*)(ar + OFF_PRJBF);
  float* x      = (float*)(ar + OFF_X);
  u16*   hbf    = (u16*)(ar + OFF_HBF);
  u16*   qkbf   = (u16*)(ar + OFF_QKBF);
  u16*   vt     = (u16*)(ar + OFF_VT);
  float* y      = (float*)(ar + OFF_Y);
  u16*   fbf    = (u16*)(ar + OFF_FBF);

  // weight conversions fp32 -> bf16
  cvt_bf16_k<<<dim3((V_VOCAB * C_DIM / 4) / 256), 256, 0, stream>>>((const float4*)wte, (ushort4*)wtebf, V_VOCAB * C_DIM / 4);
  cvt_bf16_k<<<dim3((L_LAYERS * 2 * C_DIM * C_DIM / 4) / 256), 256, 0, stream>>>((const float4*)attw, (ushort4*)attnbf, L_LAYERS * 2 * C_DIM * C_DIM / 4);
  cvt_bf16_k<<<dim3((L_LAYERS * FF_DIM * C_DIM / 4) / 256), 256, 0, stream>>>((const float4*)fcw, (ushort4*)fcbf, L_LAYERS * FF_DIM * C_DIM / 4);
  cvt_bf16_k<<<dim3((L_LAYERS * C_DIM * FF_DIM / 4) / 256), 256, 0, stream>>>((const float4*)prjw, (ushort4*)prjbf, L_LAYERS * C_DIM * FF_DIM / 4);

  embed_k<<<dim3(T_SEQ), 256, 0, stream>>>(idx, (const float4*)wte, (float4*)x);

  for (int l = 0; l < L_LAYERS; l++) {
    symln_k<<<dim3(T_SEQ), 256, 0, stream>>>(x, ln1w + l * H_HEADS, ln1b + l * H_HEADS, hbf);
    // qk = LN(x) @ attn_w^T + attn_b  -> bf16  (BM=64: 512 blocks, 2/CU)
    gemm_nt<64, 128, 2, 2, 1, 32><<<dim3((2 * C_DIM / 128) * (T_SEQ / 64)), 256, 0, stream>>>(
        hbf, C_DIM, attnbf + (size_t)l * 2 * C_DIM * C_DIM, C_DIM,
        qkbf, 2 * C_DIM, C_DIM, attb + l * 2 * C_DIM, nullptr, 0);
    vcompute_k<<<dim3(T_SEQ / 4, H_HEADS), 256, 0, stream>>>(hbf, vtmp + (size_t)l * H_HEADS * 64 * 64, vt);
    // fused flash attention -> y
    flash_k<<<dim3(T_SEQ / 64, H_HEADS), 256, 0, stream>>>(qkbf, vt, y);
    headproj_k<<<dim3(T_SEQ / 4, H_HEADS), 256, 0, stream>>>(y, ptmp + (size_t)l * H_HEADS * 64 * 64, x);
    symln_k<<<dim3(T_SEQ), 256, 0, stream>>>(x, ln2w + l * H_HEADS, ln2b + l * H_HEADS, hbf);
    // f = gelu(LN2(x) @ fc_w^T + fc_b) -> bf16  (512 blocks)
    gemm_nt<128, 128, 2, 2, 3, 16><<<dim3((FF_DIM / 128) * (T_SEQ / 128)), 256, 0, stream>>>(
        hbf, C_DIM, fcbf + (size_t)l * FF_DIM * C_DIM, C_DIM,
        fbf, FF_DIM, C_DIM, fcb + l * FF_DIM, nullptr, 0);
    // x = x + f @ proj_w^T + proj_b  (BM=64: 256 blocks, 1/CU)
    gemm_nt<64, 128, 2, 2, 4, 32><<<dim3((C_DIM / 128) * (T_SEQ / 64)), 256, 0, stream>>>(
        fbf, FF_DIM, prjbf + (size_t)l * C_DIM * FF_DIM, FF_DIM,
        x, C_DIM, FF_DIM, prjb + l * C_DIM, x, C_DIM);
  }
  symln_k<<<dim3(T_SEQ), 256, 0, stream>>>(x, lnfw, lnfb, hbf);
  // logits = LN_f(x) @ wte^T  (f32 nontemporal out; 4000 blocks)
  gemm_nt<128, 128, 2, 2, 0, 16><<<dim3((V_VOCAB / 128) * (T_SEQ / 128)), 256, 0, stream>>>(
      hbf, C_DIM, wtebf, C_DIM, out, V_VOCAB, C_DIM, nullptr, nullptr, 0);
}

// Round 5
// 837.852 us; speedup vs baseline: 1.4278x; 1.0005x over previous
//
#include <hip/hip_runtime.h>
#include <cstdint>
#include <cstddef>

// ---------------- problem constants ----------------
#define T_SEQ 2048
#define C_DIM 1024
#define H_HEADS 16
#define D_HEAD 64
#define FF_DIM 4096
#define V_VOCAB 32000
#define L_LAYERS 2

typedef unsigned short u16;
typedef short bf16x8 __attribute__((ext_vector_type(8)));
typedef float f32x4 __attribute__((ext_vector_type(4)));

__device__ inline u16 f2bf(float f) {
  unsigned u = __float_as_uint(f);
  u += 0x7fffu + ((u >> 16) & 1u);   // RNE
  return (u16)(u >> 16);
}
__device__ inline float bf2f(u16 h) { return __uint_as_float(((unsigned)h) << 16); }

// ---------------- device arena ----------------
#define OFF_WTEBF   0ULL                    // 32000*1024 bf16
#define OFF_ATTNBF  65536000ULL             // 2*2048*1024 bf16
#define OFF_FCBF    73924608ULL             // 2*4096*1024 bf16
#define OFF_PRJBF   90701824ULL             // 2*1024*4096 bf16
#define OFF_X       107479040ULL            // 2048*1024 f32 (residual stream)
#define OFF_HBF     115867648ULL            // 2048*1024 bf16 (LN out)
#define OFF_QKBF    120061952ULL            // 2048*2048 bf16 (q|k)
#define OFF_VT      128450560ULL            // 16*64*2048 bf16 (V^T per head)
#define OFF_Y       132644864ULL            // 2048*1024 f32 (attn out pre-proj)
#define OFF_FBF     141033472ULL            // 2048*4096 bf16 (gelu(fc) out)
#define ARENA_BYTES 157810688ULL

__device__ __align__(1024) unsigned char g_arena[ARENA_BYTES];

// ---------------- tiny kernels ----------------
__global__ void cvt_bf16_k(const float4* __restrict__ in, ushort4* __restrict__ out, int n4) {
  int i = blockIdx.x * 256 + threadIdx.x;
  if (i < n4) {
    float4 v = in[i];
    out[i] = make_ushort4(f2bf(v.x), f2bf(v.y), f2bf(v.z), f2bf(v.w));
  }
}

__global__ void embed_k(const int* __restrict__ idx, const float4* __restrict__ wte,
                        float4* __restrict__ x) {
  int t = blockIdx.x;
  int r = idx[t];
  x[(size_t)t * 256 + threadIdx.x] = wte[(size_t)r * 256 + threadIdx.x];
}

// per-(token, head) LayerNorm over 64 channels, scalar w/b per head; bf16 out
__global__ void symln_k(const float* __restrict__ x, const float* __restrict__ w,
                        const float* __restrict__ b, u16* __restrict__ out) {
  int t = blockIdx.x;
  int wv = threadIdx.x >> 6, lane = threadIdx.x & 63;
  #pragma unroll
  for (int hh = 0; hh < 4; hh++) {
    int h = wv * 4 + hh;
    float v = x[(size_t)t * C_DIM + h * 64 + lane];
    float s = v, s2 = v * v;
    #pragma unroll
    for (int m = 32; m; m >>= 1) { s += __shfl_xor(s, m); s2 += __shfl_xor(s2, m); }
    float mu = s * (1.f / 64.f);
    float var = s2 * (1.f / 64.f) - mu * mu;
    float n = (v - mu) * rsqrtf(var + 1e-5f) * w[h] + b[h];
    out[(size_t)t * C_DIM + h * 64 + lane] = f2bf(n);
  }
}

// v[t,h,e] = sum_d h_in[t,h,d]*v_tmp[h,e,d]  -> stored transposed vt[h][e][t] (bf16)
__global__ void vcompute_k(const u16* __restrict__ hbf, const float* __restrict__ vtmp,
                           u16* __restrict__ vt) {
  int h = blockIdx.y, t0 = blockIdx.x * 4;
  int tt = threadIdx.x >> 6, e = threadIdx.x & 63;
  __shared__ float hx[4][64];
  hx[tt][e] = bf2f(hbf[(size_t)(t0 + tt) * C_DIM + h * 64 + e]);
  __syncthreads();
  const float4* w4 = (const float4*)(vtmp + ((size_t)h * 64 + e) * 64);
  float s = 0.f;
  #pragma unroll
  for (int dd = 0; dd < 16; dd++) {
    float4 wv = w4[dd];
    s += hx[tt][dd*4+0]*wv.x + hx[tt][dd*4+1]*wv.y + hx[tt][dd*4+2]*wv.z + hx[tt][dd*4+3]*wv.w;
  }
  vt[((size_t)h * 64 + e) * T_SEQ + (t0 + tt)] = f2bf(s);
}

// x[t,h,e] += sum_d y[t,h,d]*proj_tmp[h,e,d]
__global__ void headproj_k(const float* __restrict__ y, const float* __restrict__ ptmp,
                           float* __restrict__ x) {
  int h = blockIdx.y, t0 = blockIdx.x * 4;
  int tt = threadIdx.x >> 6, e = threadIdx.x & 63;
  __shared__ float hx[4][64];
  hx[tt][e] = y[(size_t)(t0 + tt) * C_DIM + h * 64 + e];
  __syncthreads();
  const float4* w4 = (const float4*)(ptmp + ((size_t)h * 64 + e) * 64);
  float s = 0.f;
  #pragma unroll
  for (int dd = 0; dd < 16; dd++) {
    float4 wv = w4[dd];
    s += hx[tt][dd*4+0]*wv.x + hx[tt][dd*4+1]*wv.y + hx[tt][dd*4+2]*wv.z + hx[tt][dd*4+3]*wv.w;
  }
  x[(size_t)(t0 + tt) * C_DIM + h * 64 + e] += s;
}

// ---------------- generic swizzled global->LDS staging ----------------
// Stages NROWS rows of ROWBYTES bytes each; LDS holds them XOR-swizzled:
// swz(addr) = addr ^ (((addr/ROWBYTES)&7)<<4). Readers must apply same XOR.
template <int NROWS, int ROWBYTES, int WAVES>
__device__ inline void stage_rows(u16* lds, const u16* __restrict__ g, int ld,
                                  int wid, int lane) {
  constexpr int PASSES = (NROWS * ROWBYTES) / (WAVES * 1024);
  #pragma unroll
  for (int i = 0; i < PASSES; i++) {
    int base = (i * WAVES + wid) * 1024;          // wave-uniform LDS byte base
    int o = base + lane * 16;                     // this lane's linear dest
    int u = o ^ (((o / ROWBYTES) & 7) << 4);      // un-swizzled byte addr
    int row = u / ROWBYTES, colb = u % ROWBYTES;
    const u16* src = g + (size_t)row * ld + (colb >> 1);
    __builtin_amdgcn_global_load_lds((const __attribute__((address_space(1))) void*)src,
                                     (__attribute__((address_space(3))) void*)(lds + base / 2),
                                     16, 0, 0);
  }
}

// ---------------- flash attention v2 --------------------------------------
// grid (T/64, H), 256 threads (4 waves), 16 q-rows per wave.
// Fixed-max softmax (scores bounded ~|3|): P = exp(s - 8), no in-loop reduces.
__global__ __launch_bounds__(256) void flash_k(const u16* __restrict__ qk,
                                               const u16* __restrict__ vt,
                                               float* __restrict__ y) {
  int h = blockIdx.y;
  int q0 = blockIdx.x * 64;
  int tid = threadIdx.x, wid = tid >> 6, lane = tid & 63;
  int g4 = lane >> 4, l15 = lane & 15;
  __shared__ u16 Kl[128 * 64];    // [key][d]    rowbytes 128, swizzled
  __shared__ u16 Vl[64 * 128];    // [d][key]    rowbytes 256, swizzled
  __shared__ u16 Pl[64 * 128];    // [qrow][key] rowbytes 256, wave-private rows
  float slope = exp2f(-0.5f * (float)(h + 1));

  bf16x8 qf[2];
  const u16* qb = qk + (size_t)(q0 + wid * 16) * 2048 + h * 64;
  #pragma unroll
  for (int kk = 0; kk < 2; kk++)
    qf[kk] = *(const bf16x8*)(qb + (size_t)l15 * 2048 + kk * 32 + g4 * 8);

  f32x4 lsum = (f32x4){0.f, 0.f, 0.f, 0.f};
  f32x4 oacc[4];
  #pragma unroll
  for (int n = 0; n < 4; n++) oacc[n] = (f32x4){0.f, 0.f, 0.f, 0.f};

  const u16* kbase = qk + 1024 + h * 64;
  const u16* vbase = vt + (size_t)h * 64 * T_SEQ;

  for (int kt = 0; kt < T_SEQ / 128; kt++) {
    int k0 = kt * 128;
    stage_rows<128, 128, 4>(Kl, kbase + (size_t)k0 * 2048, 2048, wid, lane);
    stage_rows<64, 256, 4>(Vl, vbase + k0, T_SEQ, wid, lane);
    __syncthreads();

    f32x4 s[8];
    #pragma unroll
    for (int n = 0; n < 8; n++) s[n] = (f32x4){0.f, 0.f, 0.f, 0.f};
    #pragma unroll
    for (int kk = 0; kk < 2; kk++) {
      #pragma unroll
      for (int n = 0; n < 8; n++) {
        int r = n * 16 + l15;
        int b = (r * 128 + kk * 64 + g4 * 16) ^ ((r & 7) << 4);
        bf16x8 kf = *(const bf16x8*)((const char*)Kl + b);
        s[n] = __builtin_amdgcn_mfma_f32_16x16x32_bf16(qf[kk], kf, s[n], 0, 0, 0);
      }
    }

    int iq = q0 + wid * 16 + g4 * 4;
    #pragma unroll
    for (int n = 0; n < 8; n++) {
      int j = k0 + n * 16 + l15;
      #pragma unroll
      for (int i = 0; i < 4; i++) {
        float v = s[n][i] * 0.125f + slope * fminf((float)(j - (iq + i)), 0.f);
        float p = __expf(v - 8.f);
        lsum[i] += p;
        int pr = wid * 16 + g4 * 4 + i;
        int b = (pr * 256 + (n * 16 + l15) * 2) ^ ((pr & 7) << 4);
        *(u16*)((char*)Pl + b) = f2bf(p);
      }
    }

    #pragma unroll
    for (int kk = 0; kk < 4; kk++) {
      int pr = wid * 16 + l15;
      int pb = (pr * 256 + kk * 64 + g4 * 16) ^ ((pr & 7) << 4);
      bf16x8 pa = *(const bf16x8*)((const char*)Pl + pb);
      #pragma unroll
      for (int n = 0; n < 4; n++) {
        int d = n * 16 + l15;
        int vb = (d * 256 + kk * 64 + g4 * 16) ^ ((d & 7) << 4);
        bf16x8 vf = *(const bf16x8*)((const char*)Vl + vb);
        oacc[n] = __builtin_amdgcn_mfma_f32_16x16x32_bf16(pa, vf, oacc[n], 0, 0, 0);
      }
    }
    __syncthreads();
  }

  #pragma unroll
  for (int i = 0; i < 4; i++) {
    float v = lsum[i];
    #pragma unroll
    for (int msk = 1; msk <= 8; msk <<= 1) v += __shfl_xor(v, msk);
    lsum[i] = v;
  }
  float* yb = y + (size_t)(q0 + wid * 16) * C_DIM + h * 64;
  #pragma unroll
  for (int n = 0; n < 4; n++)
    #pragma unroll
    for (int i = 0; i < 4; i++)
      yb[(size_t)(g4 * 4 + i) * C_DIM + n * 16 + l15] = oacc[n][i] / lsum[i];
}

// ---------------- 256x256 deep-pipelined GEMM (lm_head) ---------------------
// C[m,n] = sum_k A[m,k]*B[n,k], f32 store. 8 waves (2Mx4N), BK=64, 128KB LDS
// double-buffer, counted vmcnt(8) across tiles (T3+T4), T2 swizzle, T5 setprio.
// INVARIANT (race fix vs r4): every wave does its own vmcnt THEN s_barrier
// before ANY ds_read of the tile -> all waves' global_load_lds visible.
// Buffer overwrite at t+1 is guarded by tile t's final phase barrier.
#define ASM_VMCNT8 asm volatile("s_waitcnt vmcnt(8)" ::: "memory")
#define ASM_VMCNT0 asm volatile("s_waitcnt vmcnt(0)" ::: "memory")

__global__ __launch_bounds__(512, 2) void gemm256_k(const u16* __restrict__ A, int lda,
                                                    const u16* __restrict__ B, int ldb,
                                                    float* __restrict__ C, int ldc,
                                                    int K, int MT) {
  extern __shared__ u16 sm[];
  u16* lsA = sm;              // [2][256*64] u16
  u16* lsB = sm + 32768;      // [2][256*64] u16
  int tid = threadIdx.x, wid = tid >> 6, lane = tid & 63;
  int g4 = lane >> 4, l15 = lane & 15;
  int wm = wid >> 2, wn = wid & 3;
  int nwg = gridDim.x, lin = blockIdx.x;
  int chunk = nwg >> 3;                       // nwg % 8 == 0 (bijective)
  int w = (lin & 7) * chunk + (lin >> 3);     // XCD gets contiguous chunk
  int by = w % MT, bx = w / MT;               // M-fast -> B-panel reuse
  const u16* Ab = A + (size_t)(by * 256) * lda;
  const u16* Bb = B + (size_t)(bx * 256) * ldb;

  f32x4 acc[8][4];
  #pragma unroll
  for (int m = 0; m < 8; m++)
    #pragma unroll
    for (int n = 0; n < 4; n++) acc[m][n] = (f32x4){0.f, 0.f, 0.f, 0.f};

  int NT = K >> 6;
  // prologue: stage K-tile 0 into buf 0 (8 loads/lane)
  stage_rows<256, 128, 8>(lsA, Ab, lda, wid, lane);
  stage_rows<256, 128, 8>(lsB, Bb, ldb, wid, lane);

  for (int t = 0; t < NT; ++t) {
    int cur = t & 1;
    const char* cA = (const char*)(lsA + cur * 16384);
    const char* cB = (const char*)(lsB + cur * 16384);
    if (t + 1 < NT) {
      // issue next K-tile's 8 loads; counted wait: own tile-t loads done,
      // tile-(t+1)'s 8 stay in flight across the barrier.
      stage_rows<256, 128, 8>(lsA + (cur ^ 1) * 16384, Ab + (t + 1) * 64, lda, wid, lane);
      stage_rows<256, 128, 8>(lsB + (cur ^ 1) * 16384, Bb + (t + 1) * 64, ldb, wid, lane);
      ASM_VMCNT8;
    } else {
      ASM_VMCNT0;
    }
    __builtin_amdgcn_s_barrier();            // ALL waves' tile-t staging visible
    __builtin_amdgcn_sched_barrier(0);

    bf16x8 bfr[4], af[4];
    #pragma unroll
    for (int ph = 0; ph < 4; ++ph) {
      const int kk = ph >> 1, mh = ph & 1;
      if (mh == 0) {
        #pragma unroll
        for (int n = 0; n < 4; n++) {
          int r = wn * 64 + n * 16 + l15;
          bfr[n] = *(const bf16x8*)(cB + ((r * 128 + kk * 64 + g4 * 16) ^ ((r & 7) << 4)));
        }
      }
      #pragma unroll
      for (int m = 0; m < 4; m++) {
        int r = wm * 128 + (mh * 4 + m) * 16 + l15;
        af[m] = *(const bf16x8*)(cA + ((r * 128 + kk * 64 + g4 * 16) ^ ((r & 7) << 4)));
      }
      __builtin_amdgcn_sched_barrier(0);     // pin: reads issued here
      __builtin_amdgcn_s_setprio(1);
      #pragma unroll
      for (int m = 0; m < 4; m++)            // compiler inserts counted lgkm waits
        #pragma unroll
        for (int n = 0; n < 4; n++)
          acc[mh * 4 + m][n] =
              __builtin_amdgcn_mfma_f32_16x16x32_bf16(af[m], bfr[n], acc[mh * 4 + m][n], 0, 0, 0);
      __builtin_amdgcn_s_setprio(0);
      __builtin_amdgcn_s_barrier();          // phase lock; last one guards buffer reuse
    }
  }

  int gr0 = by * 256 + wm * 128, gc0 = bx * 256 + wn * 64;
  #pragma unroll
  for (int m = 0; m < 8; m++)
    #pragma unroll
    for (int n = 0; n < 4; n++)
      #pragma unroll
      for (int i = 0; i < 4; i++)
        C[(size_t)(gr0 + m * 16 + g4 * 4 + i) * ldc + gc0 + n * 16 + l15] = acc[m][n][i];
}

// ---------------- bf16 NT GEMM (MFMA 16x16x32), BK=64, XOR-swizzled LDS ------
// EPI: 0=f32 store, 1=bias+bf16, 3=bias+gelu+bf16, 4=bias+resid+f32
// MT>0: 1D grid, M-fast work order + bijective XCD chunking (nwg%8==0).
template <int BM, int BN, int WM, int WN, int EPI, int MT>
__global__ void gemm_nt(const u16* __restrict__ A, int lda,
                        const u16* __restrict__ B, int ldb,
                        void* __restrict__ C, int ldc,
                        int K, const float* __restrict__ bias,
                        const float* __restrict__ resid, int ldr) {
  constexpr int RM = BM / WM, RN = BN / WN;
  constexpr int MR = RM / 16, NR = RN / 16;
  __shared__ u16 lsA[BM * 64];
  __shared__ u16 lsB[BN * 64];
  int tid = threadIdx.x, wid = tid >> 6, lane = tid & 63;
  int wm = wid / WN, wn = wid % WN;
  int bx, by;
  {
    int nwg = gridDim.x;
    int lin = blockIdx.x;
    int chunk = nwg >> 3;
    int w = (lin & 7) * chunk + (lin >> 3);
    by = w % MT;
    bx = w / MT;
  }
  int row0 = by * BM, col0 = bx * BN;
  const u16* Ab = A + (size_t)row0 * lda;
  const u16* Bb = B + (size_t)col0 * ldb;

  f32x4 acc[MR][NR];
  #pragma unroll
  for (int m = 0; m < MR; m++)
    #pragma unroll
    for (int n = 0; n < NR; n++) acc[m][n] = (f32x4){0.f, 0.f, 0.f, 0.f};

  for (int k0 = 0; k0 < K; k0 += 64) {
    stage_rows<BM, 128, 4>(lsA, Ab + k0, lda, wid, lane);
    stage_rows<BN, 128, 4>(lsB, Bb + k0, ldb, wid, lane);
    __syncthreads();
    #pragma unroll
    for (int kk = 0; kk < 2; kk++) {
      bf16x8 af[MR], bfr[NR];
      #pragma unroll
      for (int m = 0; m < MR; m++) {
        int r = wm * RM + m * 16 + (lane & 15);
        int bofs = (r * 128 + kk * 64 + ((lane >> 4) * 16)) ^ ((r & 7) << 4);
        af[m] = *(const bf16x8*)((const char*)lsA + bofs);
      }
      #pragma unroll
      for (int n = 0; n < NR; n++) {
        int r = wn * RN + n * 16 + (lane & 15);
        int bofs = (r * 128 + kk * 64 + ((lane >> 4) * 16)) ^ ((r & 7) << 4);
        bfr[n] = *(const bf16x8*)((const char*)lsB + bofs);
      }
      #pragma unroll
      for (int m = 0; m < MR; m++)
        #pragma unroll
        for (int n = 0; n < NR; n++)
          acc[m][n] = __builtin_amdgcn_mfma_f32_16x16x32_bf16(af[m], bfr[n], acc[m][n], 0, 0, 0);
    }
    __syncthreads();
  }

  int rbase = row0 + wm * RM, cbase = col0 + wn * RN;
  #pragma unroll
  for (int m = 0; m < MR; m++)
    #pragma unroll
    for (int n = 0; n < NR; n++)
      #pragma unroll
      for (int i = 0; i < 4; i++) {
        int gr = rbase + m * 16 + ((lane >> 4) * 4) + i;
        int gc = cbase + n * 16 + (lane & 15);
        float v = acc[m][n][i];
        if constexpr (EPI == 0) {
          ((float*)C)[(size_t)gr * ldc + gc] = v;
        } else if constexpr (EPI == 1) {
          v += bias[gc];
          ((u16*)C)[(size_t)gr * ldc + gc] = f2bf(v);
        } else if constexpr (EPI == 3) {
          v += bias[gc];
          v = 0.5f * v * (1.f + erff(v * 0.70710678118654752f));
          ((u16*)C)[(size_t)gr * ldc + gc] = f2bf(v);
        } else {
          v += bias[gc] + resid[(size_t)gr * ldr + gc];
          ((float*)C)[(size_t)gr * ldc + gc] = v;
        }
      }
}

// ---------------- host launch ----------------
extern "C" void kernel_launch(void* const* d_in, const int* in_sizes, int n_in,
                              void* d_out, int out_size, void* d_ws, size_t ws_size,
                              hipStream_t stream) {
  (void)in_sizes; (void)n_in; (void)out_size; (void)d_ws; (void)ws_size;
  const int*   idx    = (const int*)d_in[0];
  const float* wte    = (const float*)d_in[1];
  const float* ln1w   = (const float*)d_in[2];
  const float* ln1b   = (const float*)d_in[3];
  const float* ln2w   = (const float*)d_in[4];
  const float* ln2b   = (const float*)d_in[5];
  const float* lnfw   = (const float*)d_in[6];
  const float* lnfb   = (const float*)d_in[7];
  const float* attw   = (const float*)d_in[8];
  const float* attb   = (const float*)d_in[9];
  const float* vtmp   = (const float*)d_in[10];
  const float* ptmp   = (const float*)d_in[11];
  const float* fcw    = (const float*)d_in[12];
  const float* fcb    = (const float*)d_in[13];
  const float* prjw   = (const float*)d_in[14];
  const float* prjb   = (const float*)d_in[15];
  float* out = (float*)d_out;

  unsigned char* ar = nullptr;
  hipGetSymbolAddress((void**)&ar, HIP_SYMBOL(g_arena));
  u16*   wtebf  = (u16*)(ar + OFF_WTEBF);
  u16*   attnbf = (u16*)(ar + OFF_ATTNBF);
  u16*   fcbf   = (u16*)(ar + OFF_FCBF);
  u16*   prjbf  = (u16*)(ar + OFF_PRJBF);
  float* x      = (float*)(ar + OFF_X);
  u16*   hbf    = (u16*)(ar + OFF_HBF);
  u16*   qkbf   = (u16*)(ar + OFF_QKBF);
  u16*   vt     = (u16*)(ar + OFF_VT);
  float* y      = (float*)(ar + OFF_Y);
  u16*   fbf    = (u16*)(ar + OFF_FBF);

  // allow 128 KiB dynamic LDS for the 256^2 kernel (idempotent, capture-safe)
  hipFuncSetAttribute((const void*)gemm256_k,
                      hipFuncAttributeMaxDynamicSharedMemorySize, 131072);

  // weight conversions fp32 -> bf16
  cvt_bf16_k<<<dim3((V_VOCAB * C_DIM / 4) / 256), 256, 0, stream>>>((const float4*)wte, (ushort4*)wtebf, V_VOCAB * C_DIM / 4);
  cvt_bf16_k<<<dim3((L_LAYERS * 2 * C_DIM * C_DIM / 4) / 256), 256, 0, stream>>>((const float4*)attw, (ushort4*)attnbf, L_LAYERS * 2 * C_DIM * C_DIM / 4);
  cvt_bf16_k<<<dim3((L_LAYERS * FF_DIM * C_DIM / 4) / 256), 256, 0, stream>>>((const float4*)fcw, (ushort4*)fcbf, L_LAYERS * FF_DIM * C_DIM / 4);
  cvt_bf16_k<<<dim3((L_LAYERS * C_DIM * FF_DIM / 4) / 256), 256, 0, stream>>>((const float4*)prjw, (ushort4*)prjbf, L_LAYERS * C_DIM * FF_DIM / 4);

  embed_k<<<dim3(T_SEQ), 256, 0, stream>>>(idx, (const float4*)wte, (float4*)x);

  for (int l = 0; l < L_LAYERS; l++) {
    symln_k<<<dim3(T_SEQ), 256, 0, stream>>>(x, ln1w + l * H_HEADS, ln1b + l * H_HEADS, hbf);
    gemm_nt<64, 128, 2, 2, 1, 32><<<dim3((2 * C_DIM / 128) * (T_SEQ / 64)), 256, 0, stream>>>(
        hbf, C_DIM, attnbf + (size_t)l * 2 * C_DIM * C_DIM, C_DIM,
        qkbf, 2 * C_DIM, C_DIM, attb + l * 2 * C_DIM, nullptr, 0);
    vcompute_k<<<dim3(T_SEQ / 4, H_HEADS), 256, 0, stream>>>(hbf, vtmp + (size_t)l * H_HEADS * 64 * 64, vt);
    flash_k<<<dim3(T_SEQ / 64, H_HEADS), 256, 0, stream>>>(qkbf, vt, y);
    headproj_k<<<dim3(T_SEQ / 4, H_HEADS), 256, 0, stream>>>(y, ptmp + (size_t)l * H_HEADS * 64 * 64, x);
    symln_k<<<dim3(T_SEQ), 256, 0, stream>>>(x, ln2w + l * H_HEADS, ln2b + l * H_HEADS, hbf);
    gemm_nt<128, 128, 2, 2, 3, 16><<<dim3((FF_DIM / 128) * (T_SEQ / 128)), 256, 0, stream>>>(
        hbf, C_DIM, fcbf + (size_t)l * FF_DIM * C_DIM, C_DIM,
        fbf, FF_DIM, C_DIM, fcb + l * FF_DIM, nullptr, 0);
    gemm_nt<64, 128, 2, 2, 4, 32><<<dim3((C_DIM / 128) * (T_SEQ / 64)), 256, 0, stream>>>(
        fbf, FF_DIM, prjbf + (size_t)l * C_DIM * FF_DIM, FF_DIM,
        x, C_DIM, FF_DIM, prjb + l * C_DIM, x, C_DIM);
  }
  symln_k<<<dim3(T_SEQ), 256, 0, stream>>>(x, lnfw, lnfb, hbf);
  // logits = LN_f(x) @ wte^T  (pipelined 256^2: 8 M-tiles x 125 N-tiles)
  gemm256_k<<<dim3((V_VOCAB / 256) * (T_SEQ / 256)), 512, 131072, stream>>>(
      hbf, C_DIM, wtebf, C_DIM, out, V_VOCAB, C_DIM, T_SEQ / 256);
}

// Round 6
// 592.772 us; speedup vs baseline: 2.0181x; 1.4134x over previous
//
#include <hip/hip_runtime.h>
#include <cstdint>
#include <cstddef>

// ---------------- problem constants ----------------
#define T_SEQ 2048
#define C_DIM 1024
#define H_HEADS 16
#define D_HEAD 64
#define FF_DIM 4096
#define V_VOCAB 32000
#define L_LAYERS 2

typedef unsigned short u16;
typedef short bf16x8 __attribute__((ext_vector_type(8)));
typedef float f32x4 __attribute__((ext_vector_type(4)));

__device__ inline u16 f2bf(float f) {
  unsigned u = __float_as_uint(f);
  u += 0x7fffu + ((u >> 16) & 1u);   // RNE
  return (u16)(u >> 16);
}
__device__ inline float bf2f(u16 h) { return __uint_as_float(((unsigned)h) << 16); }

// ---------------- device arena ----------------
#define OFF_WTEBF   0ULL                    // 32000*1024 bf16
#define OFF_ATTNBF  65536000ULL             // 2*2048*1024 bf16
#define OFF_FCBF    73924608ULL             // 2*4096*1024 bf16
#define OFF_PRJBF   90701824ULL             // 2*1024*4096 bf16
#define OFF_X       107479040ULL            // 2048*1024 f32 (residual stream)
#define OFF_HBF     115867648ULL            // 2048*1024 bf16 (LN out)
#define OFF_QKBF    120061952ULL            // 2048*2048 bf16 (q|k)
#define OFF_VT      128450560ULL            // 16*64*2048 bf16 (V^T per head)
#define OFF_Y       132644864ULL            // 2048*1024 bf16 (attn out pre-proj)
#define OFF_FBF     141033472ULL            // 2048*4096 bf16 (gelu(fc) out)
#define OFF_VWBF    157810688ULL            // 2*16*64*64 bf16 (v_tmp)
#define OFF_PWBF    158072832ULL            // 2*16*64*64 bf16 (proj_tmp)
#define ARENA_BYTES 158334976ULL

__device__ __align__(1024) unsigned char g_arena[ARENA_BYTES];

// ---------------- tiny kernels ----------------
__global__ void cvt_bf16_k(const float4* __restrict__ in, ushort4* __restrict__ out, int n4) {
  int i = blockIdx.x * 256 + threadIdx.x;
  if (i < n4) {
    float4 v = in[i];
    out[i] = make_ushort4(f2bf(v.x), f2bf(v.y), f2bf(v.z), f2bf(v.w));
  }
}

// one launch converting attn_w, fc_w, proj_w, v_tmp, proj_tmp (elem4 segments)
__global__ void cvt_multi_k(const float4* __restrict__ s0, const float4* __restrict__ s1,
                            const float4* __restrict__ s2, const float4* __restrict__ s3,
                            const float4* __restrict__ s4,
                            ushort4* __restrict__ d0, ushort4* __restrict__ d1,
                            ushort4* __restrict__ d2, ushort4* __restrict__ d3,
                            ushort4* __restrict__ d4) {
  int g = blockIdx.x * 256 + threadIdx.x;
  const float4* s; ushort4* d; int off;
  if (g < 1048576)      { s = s0; d = d0; off = g; }
  else if (g < 3145728) { s = s1; d = d1; off = g - 1048576; }
  else if (g < 5242880) { s = s2; d = d2; off = g - 3145728; }
  else if (g < 5275648) { s = s3; d = d3; off = g - 5242880; }
  else                  { s = s4; d = d4; off = g - 5275648; }
  float4 v = s[off];
  d[off] = make_ushort4(f2bf(v.x), f2bf(v.y), f2bf(v.z), f2bf(v.w));
}

__global__ void embed_k(const int* __restrict__ idx, const float4* __restrict__ wte,
                        float4* __restrict__ x) {
  int t = blockIdx.x;
  int r = idx[t];
  x[(size_t)t * 256 + threadIdx.x] = wte[(size_t)r * 256 + threadIdx.x];
}

// per-(token, head) LayerNorm over 64 channels, scalar w/b per head; bf16 out
__global__ void symln_k(const float* __restrict__ x, const float* __restrict__ w,
                        const float* __restrict__ b, u16* __restrict__ out) {
  int t = blockIdx.x;
  int wv = threadIdx.x >> 6, lane = threadIdx.x & 63;
  #pragma unroll
  for (int hh = 0; hh < 4; hh++) {
    int h = wv * 4 + hh;
    float v = x[(size_t)t * C_DIM + h * 64 + lane];
    float s = v, s2 = v * v;
    #pragma unroll
    for (int m = 32; m; m >>= 1) { s += __shfl_xor(s, m); s2 += __shfl_xor(s2, m); }
    float mu = s * (1.f / 64.f);
    float var = s2 * (1.f / 64.f) - mu * mu;
    float n = (v - mu) * rsqrtf(var + 1e-5f) * w[h] + b[h];
    out[(size_t)t * C_DIM + h * 64 + lane] = f2bf(n);
  }
}

// ---------------- generic swizzled global->LDS staging ----------------
// Stages NROWS rows of ROWBYTES bytes each; LDS holds them XOR-swizzled:
// swz(addr) = addr ^ (((addr/ROWBYTES)&7)<<4). Readers must apply same XOR.
template <int NROWS, int ROWBYTES, int WAVES>
__device__ inline void stage_rows(u16* lds, const u16* __restrict__ g, int ld,
                                  int wid, int lane) {
  constexpr int PASSES = (NROWS * ROWBYTES) / (WAVES * 1024);
  #pragma unroll
  for (int i = 0; i < PASSES; i++) {
    int base = (i * WAVES + wid) * 1024;          // wave-uniform LDS byte base
    int o = base + lane * 16;                     // this lane's linear dest
    int u = o ^ (((o / ROWBYTES) & 7) << 4);      // un-swizzled byte addr
    int row = u / ROWBYTES, colb = u % ROWBYTES;
    const u16* src = g + (size_t)row * ld + (colb >> 1);
    __builtin_amdgcn_global_load_lds((const __attribute__((address_space(1))) void*)src,
                                     (__attribute__((address_space(3))) void*)(lds + base / 2),
                                     16, 0, 0);
  }
}

// ---------------- flash attention v2 (bf16 y output) ------------------------
// grid (T/64, H), 256 threads (4 waves), 16 q-rows per wave.
// Fixed-max softmax (scores bounded ~|3|): P = exp(s - 8), no in-loop reduces.
__global__ __launch_bounds__(256) void flash_k(const u16* __restrict__ qk,
                                               const u16* __restrict__ vt,
                                               u16* __restrict__ y) {
  int h = blockIdx.y;
  int q0 = blockIdx.x * 64;
  int tid = threadIdx.x, wid = tid >> 6, lane = tid & 63;
  int g4 = lane >> 4, l15 = lane & 15;
  __shared__ u16 Kl[128 * 64];    // [key][d]    rowbytes 128, swizzled
  __shared__ u16 Vl[64 * 128];    // [d][key]    rowbytes 256, swizzled
  __shared__ u16 Pl[64 * 128];    // [qrow][key] rowbytes 256, wave-private rows
  float slope = exp2f(-0.5f * (float)(h + 1));

  bf16x8 qf[2];
  const u16* qb = qk + (size_t)(q0 + wid * 16) * 2048 + h * 64;
  #pragma unroll
  for (int kk = 0; kk < 2; kk++)
    qf[kk] = *(const bf16x8*)(qb + (size_t)l15 * 2048 + kk * 32 + g4 * 8);

  f32x4 lsum = (f32x4){0.f, 0.f, 0.f, 0.f};
  f32x4 oacc[4];
  #pragma unroll
  for (int n = 0; n < 4; n++) oacc[n] = (f32x4){0.f, 0.f, 0.f, 0.f};

  const u16* kbase = qk + 1024 + h * 64;
  const u16* vbase = vt + (size_t)h * 64 * T_SEQ;

  for (int kt = 0; kt < T_SEQ / 128; kt++) {
    int k0 = kt * 128;
    stage_rows<128, 128, 4>(Kl, kbase + (size_t)k0 * 2048, 2048, wid, lane);
    stage_rows<64, 256, 4>(Vl, vbase + k0, T_SEQ, wid, lane);
    __syncthreads();

    f32x4 s[8];
    #pragma unroll
    for (int n = 0; n < 8; n++) s[n] = (f32x4){0.f, 0.f, 0.f, 0.f};
    #pragma unroll
    for (int kk = 0; kk < 2; kk++) {
      #pragma unroll
      for (int n = 0; n < 8; n++) {
        int r = n * 16 + l15;
        int b = (r * 128 + kk * 64 + g4 * 16) ^ ((r & 7) << 4);
        bf16x8 kf = *(const bf16x8*)((const char*)Kl + b);
        s[n] = __builtin_amdgcn_mfma_f32_16x16x32_bf16(qf[kk], kf, s[n], 0, 0, 0);
      }
    }

    int iq = q0 + wid * 16 + g4 * 4;
    #pragma unroll
    for (int n = 0; n < 8; n++) {
      int j = k0 + n * 16 + l15;
      #pragma unroll
      for (int i = 0; i < 4; i++) {
        float v = s[n][i] * 0.125f + slope * fminf((float)(j - (iq + i)), 0.f);
        float p = __expf(v - 8.f);
        lsum[i] += p;
        int pr = wid * 16 + g4 * 4 + i;
        int b = (pr * 256 + (n * 16 + l15) * 2) ^ ((pr & 7) << 4);
        *(u16*)((char*)Pl + b) = f2bf(p);
      }
    }

    #pragma unroll
    for (int kk = 0; kk < 4; kk++) {
      int pr = wid * 16 + l15;
      int pb = (pr * 256 + kk * 64 + g4 * 16) ^ ((pr & 7) << 4);
      bf16x8 pa = *(const bf16x8*)((const char*)Pl + pb);
      #pragma unroll
      for (int n = 0; n < 4; n++) {
        int d = n * 16 + l15;
        int vb = (d * 256 + kk * 64 + g4 * 16) ^ ((d & 7) << 4);
        bf16x8 vf = *(const bf16x8*)((const char*)Vl + vb);
        oacc[n] = __builtin_amdgcn_mfma_f32_16x16x32_bf16(pa, vf, oacc[n], 0, 0, 0);
      }
    }
    __syncthreads();
  }

  #pragma unroll
  for (int i = 0; i < 4; i++) {
    float v = lsum[i];
    #pragma unroll
    for (int msk = 1; msk <= 8; msk <<= 1) v += __shfl_xor(v, msk);
    lsum[i] = v;
  }
  u16* yb = y + (size_t)(q0 + wid * 16) * C_DIM + h * 64;
  #pragma unroll
  for (int n = 0; n < 4; n++)
    #pragma unroll
    for (int i = 0; i < 4; i++)
      yb[(size_t)(g4 * 4 + i) * C_DIM + n * 16 + l15] = f2bf(oacc[n][i] / lsum[i]);
}

// ---------------- 256x256 deep-pipelined GEMM (lm_head) ---------------------
// One barrier per K-tile (r5 post-mortem: phase barriers serialized LDS burst
// vs MFMA burst). vmcnt(0) is instant (loads issued a full tile earlier);
// stage(t+1) after the barrier (WAR-safe); compiler's counted lgkm waits
// overlap the 24 ds_reads with the 64 MFMAs.
#define ASM_VMCNT0 asm volatile("s_waitcnt vmcnt(0)" ::: "memory")

__global__ __launch_bounds__(512, 1) void gemm256_k(const u16* __restrict__ A, int lda,
                                                    const u16* __restrict__ B, int ldb,
                                                    float* __restrict__ C, int ldc,
                                                    int K, int MT) {
  extern __shared__ u16 sm[];
  u16* lsA = sm;              // [2][256*64] u16
  u16* lsB = sm + 32768;      // [2][256*64] u16
  int tid = threadIdx.x, wid = tid >> 6, lane = tid & 63;
  int g4 = lane >> 4, l15 = lane & 15;
  int wm = wid >> 2, wn = wid & 3;
  int nwg = gridDim.x, lin = blockIdx.x;
  int chunk = nwg >> 3;                       // nwg % 8 == 0 (bijective)
  int w = (lin & 7) * chunk + (lin >> 3);     // XCD gets contiguous chunk
  int by = w % MT, bx = w / MT;               // M-fast -> B-panel reuse
  const u16* Ab = A + (size_t)(by * 256) * lda;
  const u16* Bb = B + (size_t)(bx * 256) * ldb;

  f32x4 acc[8][4];
  #pragma unroll
  for (int m = 0; m < 8; m++)
    #pragma unroll
    for (int n = 0; n < 4; n++) acc[m][n] = (f32x4){0.f, 0.f, 0.f, 0.f};

  int NT = K >> 6;
  // prologue: stage K-tile 0 into buf 0
  stage_rows<256, 128, 8>(lsA, Ab, lda, wid, lane);
  stage_rows<256, 128, 8>(lsB, Bb, ldb, wid, lane);

  for (int t = 0; t < NT; ++t) {
    int cur = t & 1;
    const char* cA = (const char*)(lsA + cur * 16384);
    const char* cB = (const char*)(lsB + cur * 16384);
    ASM_VMCNT0;                              // tile t's own loads done (instant in steady state)
    __builtin_amdgcn_s_barrier();            // all waves' staging of tile t visible
    __builtin_amdgcn_sched_barrier(0);
    if (t + 1 < NT) {                        // WAR-safe: buf (t+1)&1 readers done before barrier
      stage_rows<256, 128, 8>(lsA + (cur ^ 1) * 16384, Ab + (t + 1) * 64, lda, wid, lane);
      stage_rows<256, 128, 8>(lsB + (cur ^ 1) * 16384, Bb + (t + 1) * 64, ldb, wid, lane);
    }
    #pragma unroll
    for (int kk = 0; kk < 2; kk++) {
      bf16x8 bfr[4], af[8];
      #pragma unroll
      for (int n = 0; n < 4; n++) {
        int r = wn * 64 + n * 16 + l15;
        bfr[n] = *(const bf16x8*)(cB + ((r * 128 + kk * 64 + g4 * 16) ^ ((r & 7) << 4)));
      }
      #pragma unroll
      for (int m = 0; m < 8; m++) {
        int r = wm * 128 + m * 16 + l15;
        af[m] = *(const bf16x8*)(cA + ((r * 128 + kk * 64 + g4 * 16) ^ ((r & 7) << 4)));
      }
      __builtin_amdgcn_s_setprio(1);
      #pragma unroll
      for (int m = 0; m < 8; m++)
        #pragma unroll
        for (int n = 0; n < 4; n++)
          acc[m][n] = __builtin_amdgcn_mfma_f32_16x16x32_bf16(af[m], bfr[n], acc[m][n], 0, 0, 0);
      __builtin_amdgcn_s_setprio(0);
    }
  }

  int gr0 = by * 256 + wm * 128, gc0 = bx * 256 + wn * 64;
  #pragma unroll
  for (int m = 0; m < 8; m++)
    #pragma unroll
    for (int n = 0; n < 4; n++)
      #pragma unroll
      for (int i = 0; i < 4; i++)
        C[(size_t)(gr0 + m * 16 + g4 * 4 + i) * ldc + gc0 + n * 16 + l15] = acc[m][n][i];
}

// ---------------- bf16 NT GEMM (MFMA 16x16x32), BK=64, XOR-swizzled LDS ------
// EPI: 0=f32, 1=bias+bf16, 2=bf16, 3=bias+gelu+bf16, 4=bias+resid+f32, 5=f32 +=
// GRID=0: 1D M-fast grid + bijective XCD chunk (nwg%8==0), z=0.
// GRID=1: x = tile index (by=lin%MT, bx=lin/MT), y = batch z with strides.
template <int BM, int BN, int WM, int WN, int EPI, int MT, int GRID>
__global__ void gemm_nt(const u16* __restrict__ A, int lda, long long sA,
                        const u16* __restrict__ B, int ldb, long long sB,
                        void* __restrict__ C, int ldc, long long sC,
                        int K, const float* __restrict__ bias,
                        const float* __restrict__ resid, int ldr) {
  constexpr int RM = BM / WM, RN = BN / WN;
  constexpr int MR = RM / 16, NR = RN / 16;
  __shared__ u16 lsA[BM * 64];
  __shared__ u16 lsB[BN * 64];
  int tid = threadIdx.x, wid = tid >> 6, lane = tid & 63;
  int wm = wid / WN, wn = wid % WN;
  int lin, z;
  if constexpr (GRID == 1) {
    lin = blockIdx.x; z = blockIdx.y;
  } else {
    int nwg = gridDim.x, l0 = blockIdx.x;
    int chunk = nwg >> 3;
    lin = (l0 & 7) * chunk + (l0 >> 3);
    z = 0;
  }
  int by = lin % MT, bx = lin / MT;
  int row0 = by * BM, col0 = bx * BN;
  const u16* Ab = A + (size_t)z * sA + (size_t)row0 * lda;
  const u16* Bb = B + (size_t)z * sB + (size_t)col0 * ldb;
  size_t cz = (size_t)z * sC;

  f32x4 acc[MR][NR];
  #pragma unroll
  for (int m = 0; m < MR; m++)
    #pragma unroll
    for (int n = 0; n < NR; n++) acc[m][n] = (f32x4){0.f, 0.f, 0.f, 0.f};

  for (int k0 = 0; k0 < K; k0 += 64) {
    stage_rows<BM, 128, 4>(lsA, Ab + k0, lda, wid, lane);
    stage_rows<BN, 128, 4>(lsB, Bb + k0, ldb, wid, lane);
    __syncthreads();
    #pragma unroll
    for (int kk = 0; kk < 2; kk++) {
      bf16x8 af[MR], bfr[NR];
      #pragma unroll
      for (int m = 0; m < MR; m++) {
        int r = wm * RM + m * 16 + (lane & 15);
        int bofs = (r * 128 + kk * 64 + ((lane >> 4) * 16)) ^ ((r & 7) << 4);
        af[m] = *(const bf16x8*)((const char*)lsA + bofs);
      }
      #pragma unroll
      for (int n = 0; n < NR; n++) {
        int r = wn * RN + n * 16 + (lane & 15);
        int bofs = (r * 128 + kk * 64 + ((lane >> 4) * 16)) ^ ((r & 7) << 4);
        bfr[n] = *(const bf16x8*)((const char*)lsB + bofs);
      }
      #pragma unroll
      for (int m = 0; m < MR; m++)
        #pragma unroll
        for (int n = 0; n < NR; n++)
          acc[m][n] = __builtin_amdgcn_mfma_f32_16x16x32_bf16(af[m], bfr[n], acc[m][n], 0, 0, 0);
    }
    __syncthreads();
  }

  int rbase = row0 + wm * RM, cbase = col0 + wn * RN;
  #pragma unroll
  for (int m = 0; m < MR; m++)
    #pragma unroll
    for (int n = 0; n < NR; n++)
      #pragma unroll
      for (int i = 0; i < 4; i++) {
        int gr = rbase + m * 16 + ((lane >> 4) * 4) + i;
        int gc = cbase + n * 16 + (lane & 15);
        size_t idx = cz + (size_t)gr * ldc + gc;
        float v = acc[m][n][i];
        if constexpr (EPI == 0) {
          ((float*)C)[idx] = v;
        } else if constexpr (EPI == 1) {
          v += bias[gc];
          ((u16*)C)[idx] = f2bf(v);
        } else if constexpr (EPI == 2) {
          ((u16*)C)[idx] = f2bf(v);
        } else if constexpr (EPI == 3) {
          v += bias[gc];
          v = 0.5f * v * (1.f + erff(v * 0.70710678118654752f));
          ((u16*)C)[idx] = f2bf(v);
        } else if constexpr (EPI == 4) {
          v += bias[gc] + resid[(size_t)gr * ldr + gc];
          ((float*)C)[idx] = v;
        } else {
          ((float*)C)[idx] += v;
        }
      }
}

// ---------------- host launch ----------------
extern "C" void kernel_launch(void* const* d_in, const int* in_sizes, int n_in,
                              void* d_out, int out_size, void* d_ws, size_t ws_size,
                              hipStream_t stream) {
  (void)in_sizes; (void)n_in; (void)out_size; (void)d_ws; (void)ws_size;
  const int*   idx    = (const int*)d_in[0];
  const float* wte    = (const float*)d_in[1];
  const float* ln1w   = (const float*)d_in[2];
  const float* ln1b   = (const float*)d_in[3];
  const float* ln2w   = (const float*)d_in[4];
  const float* ln2b   = (const float*)d_in[5];
  const float* lnfw   = (const float*)d_in[6];
  const float* lnfb   = (const float*)d_in[7];
  const float* attw   = (const float*)d_in[8];
  const float* attb   = (const float*)d_in[9];
  const float* vtmp   = (const float*)d_in[10];
  const float* ptmp   = (const float*)d_in[11];
  const float* fcw    = (const float*)d_in[12];
  const float* fcb    = (const float*)d_in[13];
  const float* prjw   = (const float*)d_in[14];
  const float* prjb   = (const float*)d_in[15];
  float* out = (float*)d_out;

  unsigned char* ar = nullptr;
  hipGetSymbolAddress((void**)&ar, HIP_SYMBOL(g_arena));
  u16*   wtebf  = (u16*)(ar + OFF_WTEBF);
  u16*   attnbf = (u16*)(ar + OFF_ATTNBF);
  u16*   fcbf   = (u16*)(ar + OFF_FCBF);
  u16*   prjbf  = (u16*)(ar + OFF_PRJBF);
  float* x      = (float*)(ar + OFF_X);
  u16*   hbf    = (u16*)(ar + OFF_HBF);
  u16*   qkbf   = (u16*)(ar + OFF_QKBF);
  u16*   vt     = (u16*)(ar + OFF_VT);
  u16*   ybf    = (u16*)(ar + OFF_Y);
  u16*   fbf    = (u16*)(ar + OFF_FBF);
  u16*   vwbf   = (u16*)(ar + OFF_VWBF);
  u16*   pwbf   = (u16*)(ar + OFF_PWBF);

  hipFuncSetAttribute((const void*)gemm256_k,
                      hipFuncAttributeMaxDynamicSharedMemorySize, 131072);

  // weight conversions fp32 -> bf16 (wte big; rest merged into one launch)
  cvt_bf16_k<<<dim3((V_VOCAB * C_DIM / 4) / 256), 256, 0, stream>>>(
      (const float4*)wte, (ushort4*)wtebf, V_VOCAB * C_DIM / 4);
  cvt_multi_k<<<dim3(20736), 256, 0, stream>>>(
      (const float4*)attw, (const float4*)fcw, (const float4*)prjw,
      (const float4*)vtmp, (const float4*)ptmp,
      (ushort4*)attnbf, (ushort4*)fcbf, (ushort4*)prjbf,
      (ushort4*)vwbf, (ushort4*)pwbf);

  embed_k<<<dim3(T_SEQ), 256, 0, stream>>>(idx, (const float4*)wte, (float4*)x);

  for (int l = 0; l < L_LAYERS; l++) {
    symln_k<<<dim3(T_SEQ), 256, 0, stream>>>(x, ln1w + l * H_HEADS, ln1b + l * H_HEADS, hbf);
    // qk = LN(x) @ attn_w^T + attn_b -> bf16
    gemm_nt<64, 128, 2, 2, 1, 32, 0><<<dim3((2 * C_DIM / 128) * (T_SEQ / 64)), 256, 0, stream>>>(
        hbf, C_DIM, 0, attnbf + (size_t)l * 2 * C_DIM * C_DIM, C_DIM, 0,
        qkbf, 2 * C_DIM, 0, C_DIM, attb + l * 2 * C_DIM, nullptr, 0);
    // vt[h][e][t] = v_tmp[h] @ LN(x)_h^T  (batched over heads, bf16 out)
    gemm_nt<64, 128, 2, 2, 2, 1, 1><<<dim3(T_SEQ / 128, H_HEADS), 256, 0, stream>>>(
        vwbf + (size_t)l * H_HEADS * 4096, 64, 4096, hbf, C_DIM, 64,
        vt, T_SEQ, (long long)64 * T_SEQ, 64, nullptr, nullptr, 0);
    // fused flash attention -> ybf
    flash_k<<<dim3(T_SEQ / 64, H_HEADS), 256, 0, stream>>>(qkbf, vt, ybf);
    // x += y_h @ proj_tmp[h]^T  (batched over heads, f32 +=)
    gemm_nt<128, 64, 4, 1, 5, 16, 1><<<dim3(T_SEQ / 128, H_HEADS), 256, 0, stream>>>(
        ybf, C_DIM, 64, pwbf + (size_t)l * H_HEADS * 4096, 64, 4096,
        x, C_DIM, 64, 64, nullptr, nullptr, 0);
    symln_k<<<dim3(T_SEQ), 256, 0, stream>>>(x, ln2w + l * H_HEADS, ln2b + l * H_HEADS, hbf);
    // f = gelu(LN2(x) @ fc_w^T + fc_b) -> bf16
    gemm_nt<128, 128, 2, 2, 3, 16, 0><<<dim3((FF_DIM / 128) * (T_SEQ / 128)), 256, 0, stream>>>(
        hbf, C_DIM, 0, fcbf + (size_t)l * FF_DIM * C_DIM, C_DIM, 0,
        fbf, FF_DIM, 0, C_DIM, fcb + l * FF_DIM, nullptr, 0);
    // x = x + f @ proj_w^T + proj_b
    gemm_nt<64, 128, 2, 2, 4, 32, 0><<<dim3((C_DIM / 128) * (T_SEQ / 64)), 256, 0, stream>>>(
        fbf, FF_DIM, 0, prjbf + (size_t)l * C_DIM * FF_DIM, FF_DIM, 0,
        x, C_DIM, 0, FF_DIM, prjb + l * C_DIM, x, C_DIM);
  }
  symln_k<<<dim3(T_SEQ), 256, 0, stream>>>(x, lnfw, lnfb, hbf);
  // logits = LN_f(x) @ wte^T  (256^2 pipelined; 8 M-tiles x 125 N-tiles)
  gemm256_k<<<dim3((V_VOCAB / 256) * (T_SEQ / 256)), 512, 131072, stream>>>(
      hbf, C_DIM, wtebf, C_DIM, out, V_VOCAB, C_DIM, T_SEQ / 256);
}